// Round 9
// baseline (377.773 us; speedup 1.0000x reference)
//
#include <hip/hip_runtime.h>
#include <hip/hip_fp16.h>

// Problem constants
constexpr int QN  = 10001;   // questions (Q+1)
constexpr int BB  = 512;     // batch
constexpr int TT  = 200;     // seq len
constexpr int QPB = 32;      // questions per block in k_perq

__device__ __forceinline__ float sigm(float x) { return 1.f / (1.f + __expf(-x)); }
__device__ __forceinline__ float tanh_fast(float x) { return 1.f - 2.f / (1.f + __expf(2.f * x)); }

// f32 pair -> packed f16x2 (RTNE via v_cvt_f16_f32 default rounding)
__device__ __forceinline__ unsigned packh_rtne(float lo, float hi) {
    return ((unsigned)__half_as_ushort(__float2half(hi)) << 16) |
            (unsigned)__half_as_ushort(__float2half(lo));
}

typedef _Float16 half2_t __attribute__((ext_vector_type(2)));
__device__ __forceinline__ half2_t u2h(unsigned u) {
    union { unsigned u; half2_t h; } x; x.u = u; return x.h;
}

// packed-f16 dot2: acc += w.lo*h.lo + w.hi*h.hi
#if __has_builtin(__builtin_amdgcn_fdot2)
__device__ __forceinline__ float fdot2u(unsigned wu, unsigned hu, float acc) {
    return __builtin_amdgcn_fdot2(u2h(wu), u2h(hu), acc, false);
}
#else
__device__ __forceinline__ float fdot2u(unsigned wu, unsigned hu, float acc) {
    float wlo = __half2float(__ushort_as_half((unsigned short)(wu & 0xffffu)));
    float whi = __half2float(__ushort_as_half((unsigned short)(wu >> 16)));
    float hlo = __half2float(__ushort_as_half((unsigned short)(hu & 0xffffu)));
    float hhi = __half2float(__ushort_as_half((unsigned short)(hu >> 16)));
    return acc + wlo * hlo + whi * hhi;
}
#endif

// barrier without the compiler's vmcnt(0) drain (keeps prefetch loads in flight)
__device__ __forceinline__ void barrier_nodrain() {
    asm volatile("s_waitcnt lgkmcnt(0)" ::: "memory");
    __builtin_amdgcn_s_barrier();
}

// ---------------------------------------------------------------------------
// Kernel 1: tiny precomputed tables (unchanged).
// ---------------------------------------------------------------------------
__global__ void k_tables(const float* __restrict__ E_c, const float* __restrict__ E_it,
                         const float* __restrict__ E_ut, const float* __restrict__ E_nh,
                         const float* __restrict__ W_fuse, const float* __restrict__ b_fuse,
                         const float* __restrict__ W_ih, const float* __restrict__ b_ih,
                         float* __restrict__ T_c, float* __restrict__ T_it,
                         float* __restrict__ T_ut, float* __restrict__ T_nh, float* __restrict__ T_na,
                         float* __restrict__ bias0, float* __restrict__ Vcorr)
{
    int blk = blockIdx.x, j = threadIdx.x; // 192 threads
    __shared__ float s_e[64];
    __shared__ float s_t[64];

    if (blk < 201) {
        if (j < 64) s_e[j] = E_c[blk * 64 + j];
        __syncthreads();
        float a = 0.f;
        #pragma unroll
        for (int k = 0; k < 64; k++) a += W_ih[j * 320 + 64 + k] * s_e[k];
        T_c[blk * 192 + j] = a;
    } else if (blk < 302) {
        int r = blk - 201;
        if (j < 64) s_e[j] = E_it[r * 64 + j];
        __syncthreads();
        float a = 0.f;
        #pragma unroll
        for (int k = 0; k < 64; k++) a += W_ih[j * 320 + 192 + k] * s_e[k];
        T_it[r * 192 + j] = a;
    } else if (blk < 605) {
        int which = (blk - 302) / 101;
        int r     = (blk - 302) % 101;
        const float* E = (which == 0) ? E_ut : E_nh;
        int fofs = which * 64;
        if (j < 64) s_e[j] = E[r * 64 + j];
        __syncthreads();
        if (j < 64) {
            float a = 0.f;
            #pragma unroll
            for (int d = 0; d < 64; d++) a += W_fuse[j * 192 + fofs + d] * s_e[d];
            s_t[j] = a;
        }
        __syncthreads();
        float a = 0.f;
        #pragma unroll
        for (int e = 0; e < 64; e++) a += W_ih[j * 320 + 256 + e] * s_t[e];
        float* outp = (which == 0) ? T_ut : ((which == 1) ? T_nh : T_na);
        outp[r * 192 + j] = a;
    } else {
        float a = b_ih[j];
        #pragma unroll
        for (int e = 0; e < 64; e++) a += W_ih[j * 320 + 256 + e] * b_fuse[e];
        bias0[j] = a;
        float v = 0.f;
        #pragma unroll
        for (int k = 0; k < 64; k++) v += W_ih[j * 320 + 128 + k];
        Vcorr[j] = v;
    }
}

// ---------------------------------------------------------------------------
// Kernel 2 v2: per-question precompute, TA-divergence fixed.
// 32 questions/block; weights staged ONCE per block into LDS with stride-66
// rows (b64 reads, <=4-way conflicts = cheap); one WAVE per question ->
// no barriers inside the question loops. Two phases reuse one 50KB buffer.
// ---------------------------------------------------------------------------
__global__ void __launch_bounds__(192) k_perq(
    const float* __restrict__ E_q, const float* __restrict__ W_ih,
    const float* __restrict__ qd_W1, const float* __restrict__ qd_b1,
    const float* __restrict__ qd_W2, const float* __restrict__ qd_b2,
    const float* __restrict__ dc_W1, const float* __restrict__ dc_b1,
    const float* __restrict__ dc_W2, const float* __restrict__ dc_b2,
    const int* __restrict__ q2c, const int* __restrict__ q2cm,
    const float* __restrict__ T_c,
    float* __restrict__ Xq, float* __restrict__ disc,
    float* __restrict__ qds, float* __restrict__ wdk)
{
    __shared__ float s_wbuf[192 * 66];     // 50.7KB: A = qd_W1(132)+dc_W1(32) rows; B = W_ih[:,0:64]
    __shared__ float s_qe[QPB][64];        // 8KB question embeddings
    __shared__ float s_wq[QPB][4];
    __shared__ int   s_cq[QPB][4];
    __shared__ float s_hidw[3][136];       // per-wave hid scratch

    const int tid = threadIdx.x, w = tid >> 6, l = tid & 63;
    const int q0 = blockIdx.x * QPB;

    // ---- stage phase-A weights (coalesced global reads) ----
    for (int i = tid; i < 132 * 64; i += 192)
        s_wbuf[(i >> 6) * 66 + (i & 63)] = qd_W1[i];
    for (int i = tid; i < 32 * 64; i += 192)
        s_wbuf[(132 + (i >> 6)) * 66 + (i & 63)] = dc_W1[i];
    for (int i = tid; i < QPB * 64; i += 192) {
        int qq = i >> 6, q = q0 + qq;
        s_qe[qq][i & 63] = E_q[(q < QN ? q : 0) * 64 + (i & 63)];
    }
    __syncthreads();

    // ---- phase A: wave w owns questions qq = w, w+3, ... (no barriers) ----
    for (int qq = w; qq < QPB; qq += 3) {
        int q = q0 + qq;
        bool valid = q < QN;
        int qc = valid ? q : 0;
        int cc[4], mm[4];
        #pragma unroll
        for (int k = 0; k < 4; k++) { cc[k] = q2c[qc * 4 + k]; mm[k] = q2cm[qc * 4 + k]; }

        float qe[64];
        #pragma unroll
        for (int k4 = 0; k4 < 16; k4++) {
            float4 v = *(const float4*)(&s_qe[qq][k4 * 4]);
            qe[4 * k4] = v.x; qe[4 * k4 + 1] = v.y; qe[4 * k4 + 2] = v.z; qe[4 * k4 + 3] = v.w;
        }

        auto rowdot = [&](int r) {
            const float* wr = s_wbuf + r * 66;
            float a = 0.f;
            #pragma unroll
            for (int j = 0; j < 32; j++) {
                float2 ww = *(const float2*)(wr + 2 * j);
                a += ww.x * qe[2 * j] + ww.y * qe[2 * j + 1];
            }
            return a;
        };

        s_hidw[w][l]      = fmaxf(rowdot(l)      + qd_b1[l],      0.f);
        s_hidw[w][64 + l] = fmaxf(rowdot(64 + l) + qd_b1[64 + l], 0.f);
        if (l < 4)
            s_hidw[w][128 + l] = fmaxf(rowdot(128 + l) + qd_b1[128 + l], 0.f);
        float dch = 0.f;
        if (l < 32) dch = fmaxf(rowdot(132 + l) + dc_b1[l], 0.f);

        // concept dots: 4 groups of 16 lanes over hid[132]
        int g = l >> 4, li = l & 15;
        int c = cc[g];
        float acc = 0.f;
        #pragma unroll
        for (int i = 0; i < 9; i++) {
            int m = li + 16 * i;
            if (m < 132) acc += qd_W2[c * 132 + m] * s_hidw[w][m];
        }
        acc += __shfl_xor(acc, 1); acc += __shfl_xor(acc, 2);
        acc += __shfl_xor(acc, 4); acc += __shfl_xor(acc, 8);
        float r0 = __shfl(acc, 0), r1 = __shfl(acc, 16);
        float r2 = __shfl(acc, 32), r3 = __shfl(acc, 48);

        float raw[4] = { sigm(r0 + qd_b2[cc[0]]), sigm(r1 + qd_b2[cc[1]]),
                         sigm(r2 + qd_b2[cc[2]]), sigm(r3 + qd_b2[cc[3]]) };
        float rel[4];
        #pragma unroll
        for (int k = 0; k < 4; k++) rel[k] = raw[k] * (float)mm[k];
        float sr = rel[0] + rel[1] + rel[2] + rel[3] + 1e-6f;

        float qsum = 0.f, wdv[4];
        #pragma unroll
        for (int k = 0; k < 4; k++) {
            float wd = 0.f;
            if (mm[k]) {
                bool dup = false;
                for (int jj = 0; jj < k; jj++)
                    if (mm[jj] && cc[jj] == cc[k]) dup = true;
                if (!dup) { wd = 1.f; qsum += raw[k]; }
            }
            wdv[k] = wd;
        }
        if (l < 4) { s_wq[qq][l] = rel[l] / sr; s_cq[qq][l] = cc[l]; }
        if (valid) {
            if (l < 4) wdk[q * 4 + l] = wdv[l];
            if (l == 0) qds[q] = qsum;
        }

        float dv = (l < 32) ? dch * dc_W2[l] : 0.f;
        dv += __shfl_xor(dv, 1);  dv += __shfl_xor(dv, 2);
        dv += __shfl_xor(dv, 4);  dv += __shfl_xor(dv, 8);
        dv += __shfl_xor(dv, 16);
        if (valid && l == 0) disc[q] = sigm(dv + dc_b2[0]) * 10.f;
    }

    // ---- phase B: restage W_ih[:,0:64], compute Xq rows ----
    __syncthreads();
    for (int i = tid; i < 192 * 64; i += 192) {
        int r = i >> 6, k = i & 63;
        s_wbuf[r * 66 + k] = W_ih[r * 320 + k];
    }
    __syncthreads();

    for (int qq = w; qq < QPB; qq += 3) {
        int q = q0 + qq;
        if (q >= QN) continue;

        float qe[64];
        #pragma unroll
        for (int k4 = 0; k4 < 16; k4++) {
            float4 v = *(const float4*)(&s_qe[qq][k4 * 4]);
            qe[4 * k4] = v.x; qe[4 * k4 + 1] = v.y; qe[4 * k4 + 2] = v.z; qe[4 * k4 + 3] = v.w;
        }
        float wq[4]; int cq[4];
        #pragma unroll
        for (int k = 0; k < 4; k++) { wq[k] = s_wq[qq][k]; cq[k] = s_cq[qq][k]; }

        #pragma unroll
        for (int rr = 0; rr < 3; rr++) {
            int row = rr * 64 + l;
            const float* wr = s_wbuf + row * 66;
            float a = 0.f;
            #pragma unroll
            for (int j = 0; j < 32; j++) {
                float2 ww = *(const float2*)(wr + 2 * j);
                a += ww.x * qe[2 * j] + ww.y * qe[2 * j + 1];
            }
            #pragma unroll
            for (int k = 0; k < 4; k++) a += wq[k] * T_c[cq[k] * 192 + row];
            Xq[q * 192 + row] = a;
        }
    }
}

// ---------------------------------------------------------------------------
// Kernel 3 v9: GRU scan. 192 threads (3 waves), lane owns gate-row tid.
//  - dot via v_dot2_f32_f16: weights = 32 packed f16 pairs (RTNE), h kept
//    PACKED f16 in per-wave LDS (32 uints) -> 32 dot2 insts vs 128 VALU ops.
//  - t-loop unrolled x2 with TWO static prefetch register sets -> true
//    2-step load-to-use distance (no rotation movs that force early vmcnt).
//  - redundant gates on all 3 waves + dbuf pre-activations -> 1 barrier/step.
// ---------------------------------------------------------------------------
__global__ void
__launch_bounds__(192)
__attribute__((amdgpu_waves_per_eu(1, 2)))
k_gru(
    const float* __restrict__ W_hh, const float* __restrict__ b_hh,
    const float* __restrict__ Xq, const float* __restrict__ Tit, const float* __restrict__ Tut,
    const float* __restrict__ Tnh, const float* __restrict__ Tna,
    const float* __restrict__ b0, const float* __restrict__ vc,
    const int* __restrict__ qseq, const int* __restrict__ cseq, const int* __restrict__ itseq,
    const int* __restrict__ utseq, const int* __restrict__ nhseq, const int* __restrict__ naseq,
    float* __restrict__ latent)
{
    const int tid = threadIdx.x, b = blockIdx.x;
    const int l = tid & 63, w = tid >> 6;

    __shared__ unsigned s_hp[3][32];   // per-wave h, packed f16 pairs
    __shared__ float s_rz[2][128];     // x+a rows 0..127, double-buffered
    __shared__ float s_xn[2][64];      // x rows 128..191
    __shared__ float s_an[2][64];      // a rows 128..191
    __shared__ int s_q[TT], s_c[TT], s_it[TT], s_ut[TT], s_nh[TT], s_na[TT];

    const int base = b * TT;
    for (int i = tid; i < TT; i += 192) {
        s_q[i]  = qseq[base + i];
        s_c[i]  = cseq[base + i];
        s_it[i] = itseq[base + i];
        s_ut[i] = utseq[base + i];
        s_nh[i] = nhseq[base + i];
        s_na[i] = naseq[base + i];
    }

    // lane's gate-row of W_hh as 32 packed f16 pairs (32 VGPRs, RTNE)
    unsigned wh[32];
    {
        const float4* wp = (const float4*)(W_hh + tid * 64);
        #pragma unroll
        for (int k = 0; k < 16; k++) {
            float4 v = wp[k];
            wh[2 * k]     = packh_rtne(v.x, v.y);
            wh[2 * k + 1] = packh_rtne(v.z, v.w);
        }
    }
    #pragma unroll
    for (int k = 0; k < 32; k++) asm volatile("" : "+v"(wh[k]));

    const float bh = b_hh[tid], b0j = b0[tid], vcj = vc[tid];

    if (l < 32) s_hp[w][l] = 0u;
    float hi = 0.f;
    __syncthreads();   // one-time: idx staging + h init

    // static prefetch sets: A = even steps, B = odd steps
    float gA0, gA1, gA2, gA3, gA4, cA;
    float gB0, gB1, gB2, gB3, gB4, cB;
    {
        int q = s_q[0], it = s_it[0], ut = s_ut[0], nh = s_nh[0], na = s_na[0];
        cA = (float)s_c[0];
        gA0 = Xq[q * 192 + tid];  gA1 = Tit[it * 192 + tid]; gA2 = Tut[ut * 192 + tid];
        gA3 = Tnh[nh * 192 + tid]; gA4 = Tna[na * 192 + tid];
    }
    {
        int q = s_q[1], it = s_it[1], ut = s_ut[1], nh = s_nh[1], na = s_na[1];
        cB = (float)s_c[1];
        gB0 = Xq[q * 192 + tid];  gB1 = Tit[it * 192 + tid]; gB2 = Tut[ut * 192 + tid];
        gB3 = Tnh[nh * 192 + tid]; gB4 = Tna[na * 192 + tid];
    }

    const uint4* hp4 = (const uint4*)s_hp[w];
    float* latp = latent + (size_t)base * 64 + l;

    for (int t = 0; t < TT; t += 2) {
        // ================= even step t: consume A, refill A for t+2 ========
        {
            float x = b0j + cA * vcj + (((gA0 + gA1) + (gA2 + gA3)) + gA4);
            if (t + 2 < TT) {
                int tt = t + 2;
                int q = s_q[tt], it = s_it[tt], ut = s_ut[tt], nh = s_nh[tt], na = s_na[tt];
                cA = (float)s_c[tt];
                gA0 = Xq[q * 192 + tid];  gA1 = Tit[it * 192 + tid]; gA2 = Tut[ut * 192 + tid];
                gA3 = Tnh[nh * 192 + tid]; gA4 = Tna[na * 192 + tid];
            }
            float a0 = 0.f, a1 = 0.f, a2 = 0.f, a3 = 0.f;
            #pragma unroll
            for (int k4 = 0; k4 < 8; k4++) {
                uint4 hh = hp4[k4];
                a0 = fdot2u(wh[4 * k4 + 0], hh.x, a0);
                a1 = fdot2u(wh[4 * k4 + 1], hh.y, a1);
                a2 = fdot2u(wh[4 * k4 + 2], hh.z, a2);
                a3 = fdot2u(wh[4 * k4 + 3], hh.w, a3);
            }
            float a = ((a0 + a1) + (a2 + a3)) + bh;
            if (tid < 128) s_rz[0][tid] = x + a;
            else { s_xn[0][tid - 128] = x; s_an[0][tid - 128] = a; }
            barrier_nodrain();

            float r = sigm(s_rz[0][l]);
            float z = sigm(s_rz[0][64 + l]);
            float n = tanh_fast(s_xn[0][l] + r * s_an[0][l]);
            hi = (1.f - z) * n + z * hi;
            float hnb = __shfl_xor(hi, 1);
            unsigned pk = (l & 1) ? packh_rtne(hnb, hi) : packh_rtne(hi, hnb);
            if (!(l & 1)) s_hp[w][l >> 1] = pk;
            if (w == 0) latp[(size_t)t * 64] = hi;
        }
        // ================= odd step t+1: consume B, refill B for t+3 =======
        {
            float x = b0j + cB * vcj + (((gB0 + gB1) + (gB2 + gB3)) + gB4);
            if (t + 3 < TT) {
                int tt = t + 3;
                int q = s_q[tt], it = s_it[tt], ut = s_ut[tt], nh = s_nh[tt], na = s_na[tt];
                cB = (float)s_c[tt];
                gB0 = Xq[q * 192 + tid];  gB1 = Tit[it * 192 + tid]; gB2 = Tut[ut * 192 + tid];
                gB3 = Tnh[nh * 192 + tid]; gB4 = Tna[na * 192 + tid];
            }
            float a0 = 0.f, a1 = 0.f, a2 = 0.f, a3 = 0.f;
            #pragma unroll
            for (int k4 = 0; k4 < 8; k4++) {
                uint4 hh = hp4[k4];
                a0 = fdot2u(wh[4 * k4 + 0], hh.x, a0);
                a1 = fdot2u(wh[4 * k4 + 1], hh.y, a1);
                a2 = fdot2u(wh[4 * k4 + 2], hh.z, a2);
                a3 = fdot2u(wh[4 * k4 + 3], hh.w, a3);
            }
            float a = ((a0 + a1) + (a2 + a3)) + bh;
            if (tid < 128) s_rz[1][tid] = x + a;
            else { s_xn[1][tid - 128] = x; s_an[1][tid - 128] = a; }
            barrier_nodrain();

            float r = sigm(s_rz[1][l]);
            float z = sigm(s_rz[1][64 + l]);
            float n = tanh_fast(s_xn[1][l] + r * s_an[1][l]);
            hi = (1.f - z) * n + z * hi;
            float hnb = __shfl_xor(hi, 1);
            unsigned pk = (l & 1) ? packh_rtne(hnb, hi) : packh_rtne(hi, hnb);
            if (!(l & 1)) s_hp[w][l >> 1] = pk;
            if (w == 0) latp[(size_t)(t + 1) * 64] = hi;
        }
    }
}

// ---------------------------------------------------------------------------
// Kernel 4: readout, one thread per output token (unchanged).
// ---------------------------------------------------------------------------
__global__ void __launch_bounds__(256, 2) k_final(
    const float* __restrict__ latent, const int* __restrict__ qseq,
    const float* __restrict__ la_W1, const float* __restrict__ la_b1,
    const float* __restrict__ la_W2, const float* __restrict__ la_b2,
    const int* __restrict__ q2c,
    const float* __restrict__ disc, const float* __restrict__ qds,
    const float* __restrict__ wdk, float* __restrict__ out)
{
    int o = blockIdx.x * blockDim.x + threadIdx.x;
    if (o >= BB * (TT - 1)) return;
    int b = o / (TT - 1), t = o - b * (TT - 1);

    const float* lat = latent + (size_t)(b * TT + t) * 64;
    float l[64];
    #pragma unroll
    for (int k4 = 0; k4 < 16; k4++) {
        float4 v = ((const float4*)lat)[k4];
        l[k4 * 4] = v.x; l[k4 * 4 + 1] = v.y; l[k4 * 4 + 2] = v.z; l[k4 * 4 + 3] = v.w;
    }

    int q = qseq[b * TT + t + 1];
    int c0 = q2c[q * 4], c1 = q2c[q * 4 + 1], c2 = q2c[q * 4 + 2], c3 = q2c[q * 4 + 3];

    float u0 = 0.f, u1 = 0.f, u2 = 0.f, u3 = 0.f;
    for (int m = 0; m < 132; m++) {
        float a = la_b1[m];
        const float* w = la_W1 + m * 64;
        #pragma unroll
        for (int k = 0; k < 64; k++) a += w[k] * l[k];
        float hm = fmaxf(a, 0.f);
        u0 += la_W2[c0 * 132 + m] * hm;
        u1 += la_W2[c1 * 132 + m] * hm;
        u2 += la_W2[c2 * 132 + m] * hm;
        u3 += la_W2[c3 * 132 + m] * hm;
    }

    float w0 = wdk[q * 4], w1 = wdk[q * 4 + 1], w2 = wdk[q * 4 + 2], w3 = wdk[q * 4 + 3];
    float us = w0 * sigm(u0 + la_b2[c0]) + w1 * sigm(u1 + la_b2[c1])
             + w2 * sigm(u2 + la_b2[c2]) + w3 * sigm(u3 + la_b2[c3]);
    float qs = qds[q];
    float y = disc[q] * (us - qs) / (qs + 1e-6f);
    out[o] = sigm(y);
}

// ---------------------------------------------------------------------------
extern "C" void kernel_launch(void* const* d_in, const int* in_sizes, int n_in,
                              void* d_out, int out_size, void* d_ws, size_t ws_size,
                              hipStream_t stream)
{
    const float* E_q    = (const float*)d_in[0];
    const float* E_c    = (const float*)d_in[1];
    const float* E_it   = (const float*)d_in[2];
    const float* E_ut   = (const float*)d_in[3];
    const float* E_nh   = (const float*)d_in[4];
    const float* W_fuse = (const float*)d_in[5];
    const float* b_fuse = (const float*)d_in[6];
    const float* W_ih   = (const float*)d_in[7];
    const float* b_ih   = (const float*)d_in[8];
    const float* W_hh   = (const float*)d_in[9];
    const float* b_hh   = (const float*)d_in[10];
    const float* qd_W1  = (const float*)d_in[11];
    const float* qd_b1  = (const float*)d_in[12];
    const float* qd_W2  = (const float*)d_in[13];
    const float* qd_b2  = (const float*)d_in[14];
    const float* la_W1  = (const float*)d_in[15];
    const float* la_b1  = (const float*)d_in[16];
    const float* la_W2  = (const float*)d_in[17];
    const float* la_b2  = (const float*)d_in[18];
    const float* dc_W1  = (const float*)d_in[19];
    const float* dc_b1  = (const float*)d_in[20];
    const float* dc_W2  = (const float*)d_in[21];
    const float* dc_b2  = (const float*)d_in[22];

    int off = (in_sizes[23] == QN * 200) ? 1 : 0;
    const int* qseq  = (const int*)d_in[23 + off];
    const int* cseq  = (const int*)d_in[24 + off];
    const int* itseq = (const int*)d_in[25 + off];
    const int* utseq = (const int*)d_in[26 + off];
    const int* nhseq = (const int*)d_in[27 + off];
    const int* naseq = (const int*)d_in[28 + off];
    const int* q2c   = (const int*)d_in[29 + off];
    const int* q2cm  = (const int*)d_in[30 + off];

    float* ws = (float*)d_ws;
    size_t o = 0;
    float* T_c  = ws + o; o += (size_t)201 * 192;
    float* Tit  = ws + o; o += (size_t)101 * 192;
    float* Tut  = ws + o; o += (size_t)101 * 192;
    float* Tnh  = ws + o; o += (size_t)101 * 192;
    float* Tna  = ws + o; o += (size_t)101 * 192;
    float* b0   = ws + o; o += 192;
    float* vc   = ws + o; o += 192;
    float* Xq   = ws + o; o += (size_t)QN * 192;
    float* disc = ws + o; o += QN;
    float* qds  = ws + o; o += QN;
    float* wdk  = ws + o; o += (size_t)QN * 4;
    float* latent = ws + o; o += (size_t)BB * TT * 64;

    float* outp = (float*)d_out;

    k_tables<<<606, 192, 0, stream>>>(E_c, E_it, E_ut, E_nh, W_fuse, b_fuse, W_ih, b_ih,
                                      T_c, Tit, Tut, Tnh, Tna, b0, vc);
    k_perq<<<(QN + QPB - 1) / QPB, 192, 0, stream>>>(E_q, W_ih, qd_W1, qd_b1, qd_W2, qd_b2,
                                                     dc_W1, dc_b1, dc_W2, dc_b2, q2c, q2cm, T_c,
                                                     Xq, disc, qds, wdk);
    k_gru<<<BB, 192, 0, stream>>>(W_hh, b_hh, Xq, Tit, Tut, Tnh, Tna, b0, vc,
                                  qseq, cseq, itseq, utseq, nhseq, naseq, latent);
    k_final<<<(BB * (TT - 1) + 255) / 256, 256, 0, stream>>>(latent, qseq, la_W1, la_b1,
                                                             la_W2, la_b2, q2c, disc, qds, wdk, outp);
}

// Round 10
// 358.066 us; speedup vs baseline: 1.0550x; 1.0550x over previous
//
#include <hip/hip_runtime.h>
#include <hip/hip_fp16.h>

// Problem constants
constexpr int QN  = 10001;   // questions (Q+1)
constexpr int BB  = 512;     // batch
constexpr int TT  = 200;     // seq len
constexpr int QPB = 32;      // questions per block in k_perq

__device__ __forceinline__ float sigm(float x) { return 1.f / (1.f + __expf(-x)); }
__device__ __forceinline__ float tanh_fast(float x) { return 1.f - 2.f / (1.f + __expf(2.f * x)); }

// f32 pair -> packed f16x2 (RTNE via v_cvt_f16_f32 default rounding)
__device__ __forceinline__ unsigned packh_rtne(float lo, float hi) {
    return ((unsigned)__half_as_ushort(__float2half(hi)) << 16) |
            (unsigned)__half_as_ushort(__float2half(lo));
}

typedef _Float16 half2_t __attribute__((ext_vector_type(2)));
__device__ __forceinline__ half2_t u2h(unsigned u) {
    union { unsigned u; half2_t h; } x; x.u = u; return x.h;
}

// packed-f16 dot2: acc += w.lo*h.lo + w.hi*h.hi
#if __has_builtin(__builtin_amdgcn_fdot2)
__device__ __forceinline__ float fdot2u(unsigned wu, unsigned hu, float acc) {
    return __builtin_amdgcn_fdot2(u2h(wu), u2h(hu), acc, false);
}
#else
__device__ __forceinline__ float fdot2u(unsigned wu, unsigned hu, float acc) {
    float wlo = __half2float(__ushort_as_half((unsigned short)(wu & 0xffffu)));
    float whi = __half2float(__ushort_as_half((unsigned short)(wu >> 16)));
    float hlo = __half2float(__ushort_as_half((unsigned short)(hu & 0xffffu)));
    float hhi = __half2float(__ushort_as_half((unsigned short)(hu >> 16)));
    return acc + wlo * hlo + whi * hhi;
}
#endif

// ---------------------------------------------------------------------------
// Kernel 1: tiny precomputed tables (unchanged).
// ---------------------------------------------------------------------------
__global__ void k_tables(const float* __restrict__ E_c, const float* __restrict__ E_it,
                         const float* __restrict__ E_ut, const float* __restrict__ E_nh,
                         const float* __restrict__ W_fuse, const float* __restrict__ b_fuse,
                         const float* __restrict__ W_ih, const float* __restrict__ b_ih,
                         float* __restrict__ T_c, float* __restrict__ T_it,
                         float* __restrict__ T_ut, float* __restrict__ T_nh, float* __restrict__ T_na,
                         float* __restrict__ bias0, float* __restrict__ Vcorr)
{
    int blk = blockIdx.x, j = threadIdx.x; // 192 threads
    __shared__ float s_e[64];
    __shared__ float s_t[64];

    if (blk < 201) {
        if (j < 64) s_e[j] = E_c[blk * 64 + j];
        __syncthreads();
        float a = 0.f;
        #pragma unroll
        for (int k = 0; k < 64; k++) a += W_ih[j * 320 + 64 + k] * s_e[k];
        T_c[blk * 192 + j] = a;
    } else if (blk < 302) {
        int r = blk - 201;
        if (j < 64) s_e[j] = E_it[r * 64 + j];
        __syncthreads();
        float a = 0.f;
        #pragma unroll
        for (int k = 0; k < 64; k++) a += W_ih[j * 320 + 192 + k] * s_e[k];
        T_it[r * 192 + j] = a;
    } else if (blk < 605) {
        int which = (blk - 302) / 101;
        int r     = (blk - 302) % 101;
        const float* E = (which == 0) ? E_ut : E_nh;
        int fofs = which * 64;
        if (j < 64) s_e[j] = E[r * 64 + j];
        __syncthreads();
        if (j < 64) {
            float a = 0.f;
            #pragma unroll
            for (int d = 0; d < 64; d++) a += W_fuse[j * 192 + fofs + d] * s_e[d];
            s_t[j] = a;
        }
        __syncthreads();
        float a = 0.f;
        #pragma unroll
        for (int e = 0; e < 64; e++) a += W_ih[j * 320 + 256 + e] * s_t[e];
        float* outp = (which == 0) ? T_ut : ((which == 1) ? T_nh : T_na);
        outp[r * 192 + j] = a;
    } else {
        float a = b_ih[j];
        #pragma unroll
        for (int e = 0; e < 64; e++) a += W_ih[j * 320 + 256 + e] * b_fuse[e];
        bias0[j] = a;
        float v = 0.f;
        #pragma unroll
        for (int k = 0; k < 64; k++) v += W_ih[j * 320 + 128 + k];
        Vcorr[j] = v;
    }
}

// ---------------------------------------------------------------------------
// Kernel 2: per-question precompute (r9 form, unchanged).
// ---------------------------------------------------------------------------
__global__ void __launch_bounds__(192) k_perq(
    const float* __restrict__ E_q, const float* __restrict__ W_ih,
    const float* __restrict__ qd_W1, const float* __restrict__ qd_b1,
    const float* __restrict__ qd_W2, const float* __restrict__ qd_b2,
    const float* __restrict__ dc_W1, const float* __restrict__ dc_b1,
    const float* __restrict__ dc_W2, const float* __restrict__ dc_b2,
    const int* __restrict__ q2c, const int* __restrict__ q2cm,
    const float* __restrict__ T_c,
    float* __restrict__ Xq, float* __restrict__ disc,
    float* __restrict__ qds, float* __restrict__ wdk)
{
    __shared__ float s_wbuf[192 * 66];
    __shared__ float s_qe[QPB][64];
    __shared__ float s_wq[QPB][4];
    __shared__ int   s_cq[QPB][4];
    __shared__ float s_hidw[3][136];

    const int tid = threadIdx.x, w = tid >> 6, l = tid & 63;
    const int q0 = blockIdx.x * QPB;

    for (int i = tid; i < 132 * 64; i += 192)
        s_wbuf[(i >> 6) * 66 + (i & 63)] = qd_W1[i];
    for (int i = tid; i < 32 * 64; i += 192)
        s_wbuf[(132 + (i >> 6)) * 66 + (i & 63)] = dc_W1[i];
    for (int i = tid; i < QPB * 64; i += 192) {
        int qq = i >> 6, q = q0 + qq;
        s_qe[qq][i & 63] = E_q[(q < QN ? q : 0) * 64 + (i & 63)];
    }
    __syncthreads();

    for (int qq = w; qq < QPB; qq += 3) {
        int q = q0 + qq;
        bool valid = q < QN;
        int qc = valid ? q : 0;
        int cc[4], mm[4];
        #pragma unroll
        for (int k = 0; k < 4; k++) { cc[k] = q2c[qc * 4 + k]; mm[k] = q2cm[qc * 4 + k]; }

        float qe[64];
        #pragma unroll
        for (int k4 = 0; k4 < 16; k4++) {
            float4 v = *(const float4*)(&s_qe[qq][k4 * 4]);
            qe[4 * k4] = v.x; qe[4 * k4 + 1] = v.y; qe[4 * k4 + 2] = v.z; qe[4 * k4 + 3] = v.w;
        }

        auto rowdot = [&](int r) {
            const float* wr = s_wbuf + r * 66;
            float a = 0.f;
            #pragma unroll
            for (int jj = 0; jj < 32; jj++) {
                float2 ww = *(const float2*)(wr + 2 * jj);
                a += ww.x * qe[2 * jj] + ww.y * qe[2 * jj + 1];
            }
            return a;
        };

        s_hidw[w][l]      = fmaxf(rowdot(l)      + qd_b1[l],      0.f);
        s_hidw[w][64 + l] = fmaxf(rowdot(64 + l) + qd_b1[64 + l], 0.f);
        if (l < 4)
            s_hidw[w][128 + l] = fmaxf(rowdot(128 + l) + qd_b1[128 + l], 0.f);
        float dch = 0.f;
        if (l < 32) dch = fmaxf(rowdot(132 + l) + dc_b1[l], 0.f);

        int g = l >> 4, li = l & 15;
        int c = cc[g];
        float acc = 0.f;
        #pragma unroll
        for (int i = 0; i < 9; i++) {
            int m = li + 16 * i;
            if (m < 132) acc += qd_W2[c * 132 + m] * s_hidw[w][m];
        }
        acc += __shfl_xor(acc, 1); acc += __shfl_xor(acc, 2);
        acc += __shfl_xor(acc, 4); acc += __shfl_xor(acc, 8);
        float r0 = __shfl(acc, 0), r1 = __shfl(acc, 16);
        float r2 = __shfl(acc, 32), r3 = __shfl(acc, 48);

        float raw[4] = { sigm(r0 + qd_b2[cc[0]]), sigm(r1 + qd_b2[cc[1]]),
                         sigm(r2 + qd_b2[cc[2]]), sigm(r3 + qd_b2[cc[3]]) };
        float rel[4];
        #pragma unroll
        for (int k = 0; k < 4; k++) rel[k] = raw[k] * (float)mm[k];
        float sr = rel[0] + rel[1] + rel[2] + rel[3] + 1e-6f;

        float qsum = 0.f, wdv[4];
        #pragma unroll
        for (int k = 0; k < 4; k++) {
            float wd = 0.f;
            if (mm[k]) {
                bool dup = false;
                for (int jj = 0; jj < k; jj++)
                    if (mm[jj] && cc[jj] == cc[k]) dup = true;
                if (!dup) { wd = 1.f; qsum += raw[k]; }
            }
            wdv[k] = wd;
        }
        if (l < 4) { s_wq[qq][l] = rel[l] / sr; s_cq[qq][l] = cc[l]; }
        if (valid) {
            if (l < 4) wdk[q * 4 + l] = wdv[l];
            if (l == 0) qds[q] = qsum;
        }

        float dv = (l < 32) ? dch * dc_W2[l] : 0.f;
        dv += __shfl_xor(dv, 1);  dv += __shfl_xor(dv, 2);
        dv += __shfl_xor(dv, 4);  dv += __shfl_xor(dv, 8);
        dv += __shfl_xor(dv, 16);
        if (valid && l == 0) disc[q] = sigm(dv + dc_b2[0]) * 10.f;
    }

    __syncthreads();
    for (int i = tid; i < 192 * 64; i += 192) {
        int r = i >> 6, k = i & 63;
        s_wbuf[r * 66 + k] = W_ih[r * 320 + k];
    }
    __syncthreads();

    for (int qq = w; qq < QPB; qq += 3) {
        int q = q0 + qq;
        if (q >= QN) continue;

        float qe[64];
        #pragma unroll
        for (int k4 = 0; k4 < 16; k4++) {
            float4 v = *(const float4*)(&s_qe[qq][k4 * 4]);
            qe[4 * k4] = v.x; qe[4 * k4 + 1] = v.y; qe[4 * k4 + 2] = v.z; qe[4 * k4 + 3] = v.w;
        }
        float wq[4]; int cq[4];
        #pragma unroll
        for (int k = 0; k < 4; k++) { wq[k] = s_wq[qq][k]; cq[k] = s_cq[qq][k]; }

        #pragma unroll
        for (int rr = 0; rr < 3; rr++) {
            int row = rr * 64 + l;
            const float* wr = s_wbuf + row * 66;
            float a = 0.f;
            #pragma unroll
            for (int jj = 0; jj < 32; jj++) {
                float2 ww = *(const float2*)(wr + 2 * jj);
                a += ww.x * qe[2 * jj] + ww.y * qe[2 * jj + 1];
            }
            #pragma unroll
            for (int k = 0; k < 4; k++) a += wq[k] * T_c[cq[k] * 192 + row];
            Xq[q * 192 + row] = a;
        }
    }
}

// ---------------------------------------------------------------------------
// Kernel 3 v10: GRU scan, ONE WAVE per sample — zero barriers, zero cross-wave
// communication. Lane j owns all three gate-rows (j, 64+j, 128+j):
//  - weights: 3 x 32 packed f16 pairs = 96 VGPRs (packed chains survive RA,
//    proven r9)
//  - gates computed fully IN-LANE after the dot: no 2nd LDS trip, no barrier;
//    the only cross-lane step is h-pair packing via __shfl_xor(1) (DPP)
//  - h exchanged through a 128B LDS buffer; within a single wave the compiler's
//    lgkmcnt ordering is the only sync needed
//  - 15 gathers/step (5 tables x 3 rows, 3 share one address +offset 256/512),
//    depth-2 A/B static prefetch
// ---------------------------------------------------------------------------
__global__ void
__launch_bounds__(64)
__attribute__((amdgpu_waves_per_eu(1, 1)))
k_gru(
    const float* __restrict__ W_hh, const float* __restrict__ b_hh,
    const float* __restrict__ Xq, const float* __restrict__ Tit, const float* __restrict__ Tut,
    const float* __restrict__ Tnh, const float* __restrict__ Tna,
    const float* __restrict__ b0, const float* __restrict__ vc,
    const int* __restrict__ qseq, const int* __restrict__ cseq, const int* __restrict__ itseq,
    const int* __restrict__ utseq, const int* __restrict__ nhseq, const int* __restrict__ naseq,
    float* __restrict__ latent)
{
    const int j = threadIdx.x, b = blockIdx.x;

    __shared__ unsigned s_hp[32];     // h as packed f16 pairs (128 B)
    __shared__ int s_ix[6 * TT];      // q | c | it | ut | nh | na

    const int base = b * TT;
    for (int i = j; i < TT; i += 64) {
        s_ix[i]          = qseq[base + i];
        s_ix[TT + i]     = cseq[base + i];
        s_ix[2 * TT + i] = itseq[base + i];
        s_ix[3 * TT + i] = utseq[base + i];
        s_ix[4 * TT + i] = nhseq[base + i];
        s_ix[5 * TT + i] = naseq[base + i];
    }

    // lane j's three gate rows of W_hh, packed f16: 96 VGPRs
    unsigned wr[32], wz[32], wn[32];
    {
        const float4* p0 = (const float4*)(W_hh + j * 64);
        const float4* p1 = (const float4*)(W_hh + (64 + j) * 64);
        const float4* p2 = (const float4*)(W_hh + (128 + j) * 64);
        #pragma unroll
        for (int k = 0; k < 16; k++) {
            float4 a = p0[k], bq = p1[k], c = p2[k];
            wr[2 * k] = packh_rtne(a.x, a.y);  wr[2 * k + 1] = packh_rtne(a.z, a.w);
            wz[2 * k] = packh_rtne(bq.x, bq.y); wz[2 * k + 1] = packh_rtne(bq.z, bq.w);
            wn[2 * k] = packh_rtne(c.x, c.y);  wn[2 * k + 1] = packh_rtne(c.z, c.w);
        }
    }
    #pragma unroll
    for (int k = 0; k < 32; k++)
        asm volatile("" : "+v"(wr[k]), "+v"(wz[k]), "+v"(wn[k]));

    const float bhr = b_hh[j], bhz = b_hh[64 + j], bhn = b_hh[128 + j];
    const float b0r = b0[j],   b0z = b0[64 + j],   b0n = b0[128 + j];
    const float vcr = vc[j],   vcz = vc[64 + j],   vcn = vc[128 + j];

    if (j < 32) s_hp[j] = 0u;
    float hj = 0.f;

    // depth-2 static prefetch sets: A = even steps, B = odd steps.
    // layout: G[0..2]=Xq rows (j,64+j,128+j), G[3..5]=Tit, G[6..8]=Tut,
    //         G[9..11]=Tnh, G[12..14]=Tna
    float A[15], B[15], cA, cB;

#define GATHER(G, CC, tt) { \
        int q_ = s_ix[tt], c_ = s_ix[TT + tt], it_ = s_ix[2 * TT + tt]; \
        int ut_ = s_ix[3 * TT + tt], nh_ = s_ix[4 * TT + tt], na_ = s_ix[5 * TT + tt]; \
        CC = (float)c_; \
        const float* xq_ = Xq  + q_  * 192 + j; \
        const float* ti_ = Tit + it_ * 192 + j; \
        const float* tu_ = Tut + ut_ * 192 + j; \
        const float* tn_ = Tnh + nh_ * 192 + j; \
        const float* ta_ = Tna + na_ * 192 + j; \
        G[0] = xq_[0]; G[1]  = xq_[64]; G[2]  = xq_[128]; \
        G[3] = ti_[0]; G[4]  = ti_[64]; G[5]  = ti_[128]; \
        G[6] = tu_[0]; G[7]  = tu_[64]; G[8]  = tu_[128]; \
        G[9] = tn_[0]; G[10] = tn_[64]; G[11] = tn_[128]; \
        G[12] = ta_[0]; G[13] = ta_[64]; G[14] = ta_[128]; \
    }

#define STEP(G, CC, tcur) { \
        float xr = b0r + CC * vcr + (((G[0] + G[3]) + (G[6] + G[9]))  + G[12]); \
        float xz = b0z + CC * vcz + (((G[1] + G[4]) + (G[7] + G[10])) + G[13]); \
        float xn = b0n + CC * vcn + (((G[2] + G[5]) + (G[8] + G[11])) + G[14]); \
        if ((tcur) + 2 < TT) GATHER(G, CC, (tcur) + 2); \
        float ar0 = 0.f, ar1 = 0.f, ar2 = 0.f, ar3 = 0.f; \
        float az0 = 0.f, az1 = 0.f, az2 = 0.f, az3 = 0.f; \
        float an0 = 0.f, an1 = 0.f, an2 = 0.f, an3 = 0.f; \
        const uint4* hp4 = (const uint4*)s_hp; \
        _Pragma("unroll") \
        for (int k4 = 0; k4 < 8; k4++) { \
            uint4 hh = hp4[k4]; \
            ar0 = fdot2u(wr[4 * k4 + 0], hh.x, ar0); \
            ar1 = fdot2u(wr[4 * k4 + 1], hh.y, ar1); \
            ar2 = fdot2u(wr[4 * k4 + 2], hh.z, ar2); \
            ar3 = fdot2u(wr[4 * k4 + 3], hh.w, ar3); \
            az0 = fdot2u(wz[4 * k4 + 0], hh.x, az0); \
            az1 = fdot2u(wz[4 * k4 + 1], hh.y, az1); \
            az2 = fdot2u(wz[4 * k4 + 2], hh.z, az2); \
            az3 = fdot2u(wz[4 * k4 + 3], hh.w, az3); \
            an0 = fdot2u(wn[4 * k4 + 0], hh.x, an0); \
            an1 = fdot2u(wn[4 * k4 + 1], hh.y, an1); \
            an2 = fdot2u(wn[4 * k4 + 2], hh.z, an2); \
            an3 = fdot2u(wn[4 * k4 + 3], hh.w, an3); \
        } \
        float ar = ((ar0 + ar1) + (ar2 + ar3)) + bhr; \
        float az = ((az0 + az1) + (az2 + az3)) + bhz; \
        float an = ((an0 + an1) + (an2 + an3)) + bhn; \
        float r = sigm(xr + ar); \
        float z = sigm(xz + az); \
        float n = tanh_fast(xn + r * an); \
        hj = (1.f - z) * n + z * hj; \
        latent[(size_t)(base + (tcur)) * 64 + j] = hj; \
        float hnb = __shfl_xor(hj, 1); \
        unsigned pk = (j & 1) ? packh_rtne(hnb, hj) : packh_rtne(hj, hnb); \
        if (!(j & 1)) s_hp[j >> 1] = pk; \
    }

    GATHER(A, cA, 0);
    GATHER(B, cB, 1);

    for (int t = 0; t < TT; t += 2) {
        STEP(A, cA, t);
        STEP(B, cB, t + 1);
    }
#undef STEP
#undef GATHER
}

// ---------------------------------------------------------------------------
// Kernel 4: readout, one thread per output token (unchanged).
// ---------------------------------------------------------------------------
__global__ void __launch_bounds__(256, 2) k_final(
    const float* __restrict__ latent, const int* __restrict__ qseq,
    const float* __restrict__ la_W1, const float* __restrict__ la_b1,
    const float* __restrict__ la_W2, const float* __restrict__ la_b2,
    const int* __restrict__ q2c,
    const float* __restrict__ disc, const float* __restrict__ qds,
    const float* __restrict__ wdk, float* __restrict__ out)
{
    int o = blockIdx.x * blockDim.x + threadIdx.x;
    if (o >= BB * (TT - 1)) return;
    int b = o / (TT - 1), t = o - b * (TT - 1);

    const float* lat = latent + (size_t)(b * TT + t) * 64;
    float l[64];
    #pragma unroll
    for (int k4 = 0; k4 < 16; k4++) {
        float4 v = ((const float4*)lat)[k4];
        l[k4 * 4] = v.x; l[k4 * 4 + 1] = v.y; l[k4 * 4 + 2] = v.z; l[k4 * 4 + 3] = v.w;
    }

    int q = qseq[b * TT + t + 1];
    int c0 = q2c[q * 4], c1 = q2c[q * 4 + 1], c2 = q2c[q * 4 + 2], c3 = q2c[q * 4 + 3];

    float u0 = 0.f, u1 = 0.f, u2 = 0.f, u3 = 0.f;
    for (int m = 0; m < 132; m++) {
        float a = la_b1[m];
        const float* w = la_W1 + m * 64;
        #pragma unroll
        for (int k = 0; k < 64; k++) a += w[k] * l[k];
        float hm = fmaxf(a, 0.f);
        u0 += la_W2[c0 * 132 + m] * hm;
        u1 += la_W2[c1 * 132 + m] * hm;
        u2 += la_W2[c2 * 132 + m] * hm;
        u3 += la_W2[c3 * 132 + m] * hm;
    }

    float w0 = wdk[q * 4], w1 = wdk[q * 4 + 1], w2 = wdk[q * 4 + 2], w3 = wdk[q * 4 + 3];
    float us = w0 * sigm(u0 + la_b2[c0]) + w1 * sigm(u1 + la_b2[c1])
             + w2 * sigm(u2 + la_b2[c2]) + w3 * sigm(u3 + la_b2[c3]);
    float qs = qds[q];
    float y = disc[q] * (us - qs) / (qs + 1e-6f);
    out[o] = sigm(y);
}

// ---------------------------------------------------------------------------
extern "C" void kernel_launch(void* const* d_in, const int* in_sizes, int n_in,
                              void* d_out, int out_size, void* d_ws, size_t ws_size,
                              hipStream_t stream)
{
    const float* E_q    = (const float*)d_in[0];
    const float* E_c    = (const float*)d_in[1];
    const float* E_it   = (const float*)d_in[2];
    const float* E_ut   = (const float*)d_in[3];
    const float* E_nh   = (const float*)d_in[4];
    const float* W_fuse = (const float*)d_in[5];
    const float* b_fuse = (const float*)d_in[6];
    const float* W_ih   = (const float*)d_in[7];
    const float* b_ih   = (const float*)d_in[8];
    const float* W_hh   = (const float*)d_in[9];
    const float* b_hh   = (const float*)d_in[10];
    const float* qd_W1  = (const float*)d_in[11];
    const float* qd_b1  = (const float*)d_in[12];
    const float* qd_W2  = (const float*)d_in[13];
    const float* qd_b2  = (const float*)d_in[14];
    const float* la_W1  = (const float*)d_in[15];
    const float* la_b1  = (const float*)d_in[16];
    const float* la_W2  = (const float*)d_in[17];
    const float* la_b2  = (const float*)d_in[18];
    const float* dc_W1  = (const float*)d_in[19];
    const float* dc_b1  = (const float*)d_in[20];
    const float* dc_W2  = (const float*)d_in[21];
    const float* dc_b2  = (const float*)d_in[22];

    int off = (in_sizes[23] == QN * 200) ? 1 : 0;
    const int* qseq  = (const int*)d_in[23 + off];
    const int* cseq  = (const int*)d_in[24 + off];
    const int* itseq = (const int*)d_in[25 + off];
    const int* utseq = (const int*)d_in[26 + off];
    const int* nhseq = (const int*)d_in[27 + off];
    const int* naseq = (const int*)d_in[28 + off];
    const int* q2c   = (const int*)d_in[29 + off];
    const int* q2cm  = (const int*)d_in[30 + off];

    float* ws = (float*)d_ws;
    size_t o = 0;
    float* T_c  = ws + o; o += (size_t)201 * 192;
    float* Tit  = ws + o; o += (size_t)101 * 192;
    float* Tut  = ws + o; o += (size_t)101 * 192;
    float* Tnh  = ws + o; o += (size_t)101 * 192;
    float* Tna  = ws + o; o += (size_t)101 * 192;
    float* b0   = ws + o; o += 192;
    float* vc   = ws + o; o += 192;
    float* Xq   = ws + o; o += (size_t)QN * 192;
    float* disc = ws + o; o += QN;
    float* qds  = ws + o; o += QN;
    float* wdk  = ws + o; o += (size_t)QN * 4;
    float* latent = ws + o; o += (size_t)BB * TT * 64;

    float* outp = (float*)d_out;

    k_tables<<<606, 192, 0, stream>>>(E_c, E_it, E_ut, E_nh, W_fuse, b_fuse, W_ih, b_ih,
                                      T_c, Tit, Tut, Tnh, Tna, b0, vc);
    k_perq<<<(QN + QPB - 1) / QPB, 192, 0, stream>>>(E_q, W_ih, qd_W1, qd_b1, qd_W2, qd_b2,
                                                     dc_W1, dc_b1, dc_W2, dc_b2, q2c, q2cm, T_c,
                                                     Xq, disc, qds, wdk);
    k_gru<<<BB, 64, 0, stream>>>(W_hh, b_hh, Xq, Tit, Tut, Tnh, Tna, b0, vc,
                                 qseq, cseq, itseq, utseq, nhseq, naseq, latent);
    k_final<<<(BB * (TT - 1) + 255) / 256, 256, 0, stream>>>(latent, qseq, la_W1, la_b1,
                                                             la_W2, la_b2, q2c, disc, qds, wdk, outp);
}

// Round 11
// 335.756 us; speedup vs baseline: 1.1251x; 1.0664x over previous
//
#include <hip/hip_runtime.h>
#include <hip/hip_fp16.h>

// Problem constants
constexpr int QN  = 10001;   // questions (Q+1)
constexpr int BB  = 512;     // batch
constexpr int TT  = 200;     // seq len
constexpr int QPB = 32;      // questions per block in k_perq

__device__ __forceinline__ float sigm(float x) { return 1.f / (1.f + __expf(-x)); }
__device__ __forceinline__ float tanh_fast(float x) { return 1.f - 2.f / (1.f + __expf(2.f * x)); }

// f32 pair -> packed f16x2 (RTNE via v_cvt_f16_f32 default rounding)
__device__ __forceinline__ unsigned packh_rtne(float lo, float hi) {
    return ((unsigned)__half_as_ushort(__float2half(hi)) << 16) |
            (unsigned)__half_as_ushort(__float2half(lo));
}

typedef _Float16 half2_t __attribute__((ext_vector_type(2)));
__device__ __forceinline__ half2_t u2h(unsigned u) {
    union { unsigned u; half2_t h; } x; x.u = u; return x.h;
}

// packed-f16 dot2: acc += w.lo*h.lo + w.hi*h.hi
#if __has_builtin(__builtin_amdgcn_fdot2)
__device__ __forceinline__ float fdot2u(unsigned wu, unsigned hu, float acc) {
    return __builtin_amdgcn_fdot2(u2h(wu), u2h(hu), acc, false);
}
#else
__device__ __forceinline__ float fdot2u(unsigned wu, unsigned hu, float acc) {
    float wlo = __half2float(__ushort_as_half((unsigned short)(wu & 0xffffu)));
    float whi = __half2float(__ushort_as_half((unsigned short)(wu >> 16)));
    float hlo = __half2float(__ushort_as_half((unsigned short)(hu & 0xffffu)));
    float hhi = __half2float(__ushort_as_half((unsigned short)(hu >> 16)));
    return acc + wlo * hlo + whi * hhi;
}
#endif

// ---------------------------------------------------------------------------
// Kernel 1: tiny precomputed tables (unchanged).
// ---------------------------------------------------------------------------
__global__ void k_tables(const float* __restrict__ E_c, const float* __restrict__ E_it,
                         const float* __restrict__ E_ut, const float* __restrict__ E_nh,
                         const float* __restrict__ W_fuse, const float* __restrict__ b_fuse,
                         const float* __restrict__ W_ih, const float* __restrict__ b_ih,
                         float* __restrict__ T_c, float* __restrict__ T_it,
                         float* __restrict__ T_ut, float* __restrict__ T_nh, float* __restrict__ T_na,
                         float* __restrict__ bias0, float* __restrict__ Vcorr)
{
    int blk = blockIdx.x, j = threadIdx.x; // 192 threads
    __shared__ float s_e[64];
    __shared__ float s_t[64];

    if (blk < 201) {
        if (j < 64) s_e[j] = E_c[blk * 64 + j];
        __syncthreads();
        float a = 0.f;
        #pragma unroll
        for (int k = 0; k < 64; k++) a += W_ih[j * 320 + 64 + k] * s_e[k];
        T_c[blk * 192 + j] = a;
    } else if (blk < 302) {
        int r = blk - 201;
        if (j < 64) s_e[j] = E_it[r * 64 + j];
        __syncthreads();
        float a = 0.f;
        #pragma unroll
        for (int k = 0; k < 64; k++) a += W_ih[j * 320 + 192 + k] * s_e[k];
        T_it[r * 192 + j] = a;
    } else if (blk < 605) {
        int which = (blk - 302) / 101;
        int r     = (blk - 302) % 101;
        const float* E = (which == 0) ? E_ut : E_nh;
        int fofs = which * 64;
        if (j < 64) s_e[j] = E[r * 64 + j];
        __syncthreads();
        if (j < 64) {
            float a = 0.f;
            #pragma unroll
            for (int d = 0; d < 64; d++) a += W_fuse[j * 192 + fofs + d] * s_e[d];
            s_t[j] = a;
        }
        __syncthreads();
        float a = 0.f;
        #pragma unroll
        for (int e = 0; e < 64; e++) a += W_ih[j * 320 + 256 + e] * s_t[e];
        float* outp = (which == 0) ? T_ut : ((which == 1) ? T_nh : T_na);
        outp[r * 192 + j] = a;
    } else {
        float a = b_ih[j];
        #pragma unroll
        for (int e = 0; e < 64; e++) a += W_ih[j * 320 + 256 + e] * b_fuse[e];
        bias0[j] = a;
        float v = 0.f;
        #pragma unroll
        for (int k = 0; k < 64; k++) v += W_ih[j * 320 + 128 + k];
        Vcorr[j] = v;
    }
}

// ---------------------------------------------------------------------------
// Kernel 2: per-question precompute (r9 form, unchanged).
// ---------------------------------------------------------------------------
__global__ void __launch_bounds__(192) k_perq(
    const float* __restrict__ E_q, const float* __restrict__ W_ih,
    const float* __restrict__ qd_W1, const float* __restrict__ qd_b1,
    const float* __restrict__ qd_W2, const float* __restrict__ qd_b2,
    const float* __restrict__ dc_W1, const float* __restrict__ dc_b1,
    const float* __restrict__ dc_W2, const float* __restrict__ dc_b2,
    const int* __restrict__ q2c, const int* __restrict__ q2cm,
    const float* __restrict__ T_c,
    float* __restrict__ Xq, float* __restrict__ disc,
    float* __restrict__ qds, float* __restrict__ wdk)
{
    __shared__ float s_wbuf[192 * 66];
    __shared__ float s_qe[QPB][64];
    __shared__ float s_wq[QPB][4];
    __shared__ int   s_cq[QPB][4];
    __shared__ float s_hidw[3][136];

    const int tid = threadIdx.x, w = tid >> 6, l = tid & 63;
    const int q0 = blockIdx.x * QPB;

    for (int i = tid; i < 132 * 64; i += 192)
        s_wbuf[(i >> 6) * 66 + (i & 63)] = qd_W1[i];
    for (int i = tid; i < 32 * 64; i += 192)
        s_wbuf[(132 + (i >> 6)) * 66 + (i & 63)] = dc_W1[i];
    for (int i = tid; i < QPB * 64; i += 192) {
        int qq = i >> 6, q = q0 + qq;
        s_qe[qq][i & 63] = E_q[(q < QN ? q : 0) * 64 + (i & 63)];
    }
    __syncthreads();

    for (int qq = w; qq < QPB; qq += 3) {
        int q = q0 + qq;
        bool valid = q < QN;
        int qc = valid ? q : 0;
        int cc[4], mm[4];
        #pragma unroll
        for (int k = 0; k < 4; k++) { cc[k] = q2c[qc * 4 + k]; mm[k] = q2cm[qc * 4 + k]; }

        float qe[64];
        #pragma unroll
        for (int k4 = 0; k4 < 16; k4++) {
            float4 v = *(const float4*)(&s_qe[qq][k4 * 4]);
            qe[4 * k4] = v.x; qe[4 * k4 + 1] = v.y; qe[4 * k4 + 2] = v.z; qe[4 * k4 + 3] = v.w;
        }

        auto rowdot = [&](int r) {
            const float* wr = s_wbuf + r * 66;
            float a = 0.f;
            #pragma unroll
            for (int jj = 0; jj < 32; jj++) {
                float2 ww = *(const float2*)(wr + 2 * jj);
                a += ww.x * qe[2 * jj] + ww.y * qe[2 * jj + 1];
            }
            return a;
        };

        s_hidw[w][l]      = fmaxf(rowdot(l)      + qd_b1[l],      0.f);
        s_hidw[w][64 + l] = fmaxf(rowdot(64 + l) + qd_b1[64 + l], 0.f);
        if (l < 4)
            s_hidw[w][128 + l] = fmaxf(rowdot(128 + l) + qd_b1[128 + l], 0.f);
        float dch = 0.f;
        if (l < 32) dch = fmaxf(rowdot(132 + l) + dc_b1[l], 0.f);

        int g = l >> 4, li = l & 15;
        int c = cc[g];
        float acc = 0.f;
        #pragma unroll
        for (int i = 0; i < 9; i++) {
            int m = li + 16 * i;
            if (m < 132) acc += qd_W2[c * 132 + m] * s_hidw[w][m];
        }
        acc += __shfl_xor(acc, 1); acc += __shfl_xor(acc, 2);
        acc += __shfl_xor(acc, 4); acc += __shfl_xor(acc, 8);
        float r0 = __shfl(acc, 0), r1 = __shfl(acc, 16);
        float r2 = __shfl(acc, 32), r3 = __shfl(acc, 48);

        float raw[4] = { sigm(r0 + qd_b2[cc[0]]), sigm(r1 + qd_b2[cc[1]]),
                         sigm(r2 + qd_b2[cc[2]]), sigm(r3 + qd_b2[cc[3]]) };
        float rel[4];
        #pragma unroll
        for (int k = 0; k < 4; k++) rel[k] = raw[k] * (float)mm[k];
        float sr = rel[0] + rel[1] + rel[2] + rel[3] + 1e-6f;

        float qsum = 0.f, wdv[4];
        #pragma unroll
        for (int k = 0; k < 4; k++) {
            float wd = 0.f;
            if (mm[k]) {
                bool dup = false;
                for (int jj = 0; jj < k; jj++)
                    if (mm[jj] && cc[jj] == cc[k]) dup = true;
                if (!dup) { wd = 1.f; qsum += raw[k]; }
            }
            wdv[k] = wd;
        }
        if (l < 4) { s_wq[qq][l] = rel[l] / sr; s_cq[qq][l] = cc[l]; }
        if (valid) {
            if (l < 4) wdk[q * 4 + l] = wdv[l];
            if (l == 0) qds[q] = qsum;
        }

        float dv = (l < 32) ? dch * dc_W2[l] : 0.f;
        dv += __shfl_xor(dv, 1);  dv += __shfl_xor(dv, 2);
        dv += __shfl_xor(dv, 4);  dv += __shfl_xor(dv, 8);
        dv += __shfl_xor(dv, 16);
        if (valid && l == 0) disc[q] = sigm(dv + dc_b2[0]) * 10.f;
    }

    __syncthreads();
    for (int i = tid; i < 192 * 64; i += 192) {
        int r = i >> 6, k = i & 63;
        s_wbuf[r * 66 + k] = W_ih[r * 320 + k];
    }
    __syncthreads();

    for (int qq = w; qq < QPB; qq += 3) {
        int q = q0 + qq;
        if (q >= QN) continue;

        float qe[64];
        #pragma unroll
        for (int k4 = 0; k4 < 16; k4++) {
            float4 v = *(const float4*)(&s_qe[qq][k4 * 4]);
            qe[4 * k4] = v.x; qe[4 * k4 + 1] = v.y; qe[4 * k4 + 2] = v.z; qe[4 * k4 + 3] = v.w;
        }
        float wq[4]; int cq[4];
        #pragma unroll
        for (int k = 0; k < 4; k++) { wq[k] = s_wq[qq][k]; cq[k] = s_cq[qq][k]; }

        #pragma unroll
        for (int rr = 0; rr < 3; rr++) {
            int row = rr * 64 + l;
            const float* wr = s_wbuf + row * 66;
            float a = 0.f;
            #pragma unroll
            for (int jj = 0; jj < 32; jj++) {
                float2 ww = *(const float2*)(wr + 2 * jj);
                a += ww.x * qe[2 * jj] + ww.y * qe[2 * jj + 1];
            }
            #pragma unroll
            for (int k = 0; k < 4; k++) a += wq[k] * T_c[cq[k] * 192 + row];
            Xq[q * 192 + row] = a;
        }
    }
}

// ---------------------------------------------------------------------------
// Kernel 3 v11: one wave per sample (r10) + DEPTH-4 static prefetch.
// r10 evidence: VALUBusy 27% at 2 waves/CU -> ~60% of each step is stall;
// Xq (7.7MB > per-XCD L2) random gathers at ~L3 latency with only ~1 step of
// issue-to-use distance. Four static G-sets give ~3 steps (~1500cy) of cover.
// ---------------------------------------------------------------------------
__global__ void
__launch_bounds__(64)
__attribute__((amdgpu_waves_per_eu(1, 1)))
k_gru(
    const float* __restrict__ W_hh, const float* __restrict__ b_hh,
    const float* __restrict__ Xq, const float* __restrict__ Tit, const float* __restrict__ Tut,
    const float* __restrict__ Tnh, const float* __restrict__ Tna,
    const float* __restrict__ b0, const float* __restrict__ vc,
    const int* __restrict__ qseq, const int* __restrict__ cseq, const int* __restrict__ itseq,
    const int* __restrict__ utseq, const int* __restrict__ nhseq, const int* __restrict__ naseq,
    float* __restrict__ latent)
{
    const int j = threadIdx.x, b = blockIdx.x;

    __shared__ unsigned s_hp[32];     // h as packed f16 pairs (128 B)
    __shared__ int s_ix[6 * TT];      // q | c | it | ut | nh | na

    const int base = b * TT;
    for (int i = j; i < TT; i += 64) {
        s_ix[i]          = qseq[base + i];
        s_ix[TT + i]     = cseq[base + i];
        s_ix[2 * TT + i] = itseq[base + i];
        s_ix[3 * TT + i] = utseq[base + i];
        s_ix[4 * TT + i] = nhseq[base + i];
        s_ix[5 * TT + i] = naseq[base + i];
    }

    // lane j's three gate rows of W_hh, packed f16: 96 VGPRs
    unsigned wr[32], wz[32], wn[32];
    {
        const float4* p0 = (const float4*)(W_hh + j * 64);
        const float4* p1 = (const float4*)(W_hh + (64 + j) * 64);
        const float4* p2 = (const float4*)(W_hh + (128 + j) * 64);
        #pragma unroll
        for (int k = 0; k < 16; k++) {
            float4 a = p0[k], bq = p1[k], c = p2[k];
            wr[2 * k] = packh_rtne(a.x, a.y);  wr[2 * k + 1] = packh_rtne(a.z, a.w);
            wz[2 * k] = packh_rtne(bq.x, bq.y); wz[2 * k + 1] = packh_rtne(bq.z, bq.w);
            wn[2 * k] = packh_rtne(c.x, c.y);  wn[2 * k + 1] = packh_rtne(c.z, c.w);
        }
    }
    #pragma unroll
    for (int k = 0; k < 32; k++)
        asm volatile("" : "+v"(wr[k]), "+v"(wz[k]), "+v"(wn[k]));

    const float bhr = b_hh[j], bhz = b_hh[64 + j], bhn = b_hh[128 + j];
    const float b0r = b0[j],   b0z = b0[64 + j],   b0n = b0[128 + j];
    const float vcr = vc[j],   vcz = vc[64 + j],   vcn = vc[128 + j];

    if (j < 32) s_hp[j] = 0u;
    float hj = 0.f;

    // depth-4 static prefetch sets A/B/C/D (steps t, t+1, t+2, t+3)
    float A[15], B[15], C[15], D[15], cA, cB, cC, cD;

#define GATHER(G, CC, tt) { \
        int q_ = s_ix[tt], c_ = s_ix[TT + tt], it_ = s_ix[2 * TT + tt]; \
        int ut_ = s_ix[3 * TT + tt], nh_ = s_ix[4 * TT + tt], na_ = s_ix[5 * TT + tt]; \
        CC = (float)c_; \
        const float* xq_ = Xq  + q_  * 192 + j; \
        const float* ti_ = Tit + it_ * 192 + j; \
        const float* tu_ = Tut + ut_ * 192 + j; \
        const float* tn_ = Tnh + nh_ * 192 + j; \
        const float* ta_ = Tna + na_ * 192 + j; \
        G[0] = xq_[0]; G[1]  = xq_[64]; G[2]  = xq_[128]; \
        G[3] = ti_[0]; G[4]  = ti_[64]; G[5]  = ti_[128]; \
        G[6] = tu_[0]; G[7]  = tu_[64]; G[8]  = tu_[128]; \
        G[9] = tn_[0]; G[10] = tn_[64]; G[11] = tn_[128]; \
        G[12] = ta_[0]; G[13] = ta_[64]; G[14] = ta_[128]; \
    }

#define STEP(G, CC, tcur) { \
        float xr = b0r + CC * vcr + (((G[0] + G[3]) + (G[6] + G[9]))  + G[12]); \
        float xz = b0z + CC * vcz + (((G[1] + G[4]) + (G[7] + G[10])) + G[13]); \
        float xn = b0n + CC * vcn + (((G[2] + G[5]) + (G[8] + G[11])) + G[14]); \
        if ((tcur) + 4 < TT) GATHER(G, CC, (tcur) + 4); \
        float ar0 = 0.f, ar1 = 0.f, ar2 = 0.f, ar3 = 0.f; \
        float az0 = 0.f, az1 = 0.f, az2 = 0.f, az3 = 0.f; \
        float an0 = 0.f, an1 = 0.f, an2 = 0.f, an3 = 0.f; \
        const uint4* hp4 = (const uint4*)s_hp; \
        _Pragma("unroll") \
        for (int k4 = 0; k4 < 8; k4++) { \
            uint4 hh = hp4[k4]; \
            ar0 = fdot2u(wr[4 * k4 + 0], hh.x, ar0); \
            ar1 = fdot2u(wr[4 * k4 + 1], hh.y, ar1); \
            ar2 = fdot2u(wr[4 * k4 + 2], hh.z, ar2); \
            ar3 = fdot2u(wr[4 * k4 + 3], hh.w, ar3); \
            az0 = fdot2u(wz[4 * k4 + 0], hh.x, az0); \
            az1 = fdot2u(wz[4 * k4 + 1], hh.y, az1); \
            az2 = fdot2u(wz[4 * k4 + 2], hh.z, az2); \
            az3 = fdot2u(wz[4 * k4 + 3], hh.w, az3); \
            an0 = fdot2u(wn[4 * k4 + 0], hh.x, an0); \
            an1 = fdot2u(wn[4 * k4 + 1], hh.y, an1); \
            an2 = fdot2u(wn[4 * k4 + 2], hh.z, an2); \
            an3 = fdot2u(wn[4 * k4 + 3], hh.w, an3); \
        } \
        float ar = ((ar0 + ar1) + (ar2 + ar3)) + bhr; \
        float az = ((az0 + az1) + (az2 + az3)) + bhz; \
        float an = ((an0 + an1) + (an2 + an3)) + bhn; \
        float r = sigm(xr + ar); \
        float z = sigm(xz + az); \
        float n = tanh_fast(xn + r * an); \
        hj = (1.f - z) * n + z * hj; \
        latent[(size_t)(base + (tcur)) * 64 + j] = hj; \
        float hnb = __shfl_xor(hj, 1); \
        unsigned pk = (j & 1) ? packh_rtne(hnb, hj) : packh_rtne(hj, hnb); \
        if (!(j & 1)) s_hp[j >> 1] = pk; \
    }

    GATHER(A, cA, 0);
    GATHER(B, cB, 1);
    GATHER(C, cC, 2);
    GATHER(D, cD, 3);

    for (int t = 0; t < TT; t += 4) {
        STEP(A, cA, t);
        STEP(B, cB, t + 1);
        STEP(C, cC, t + 2);
        STEP(D, cD, t + 3);
    }
#undef STEP
#undef GATHER
}

// ---------------------------------------------------------------------------
// Kernel 4 v2: readout with la_W2 staged in LDS as f16 (52.8KB).
// r10 analysis: the 4x random-row la_W2 gathers were ~215MB of uncoalesced
// L2/L3 traffic across the launch. One coalesced 105KB stage per block kills
// that. f16 weight error ~5e-4 on u -> ~1e-3 on y (threshold 1.26e-2).
// ---------------------------------------------------------------------------
__global__ void __launch_bounds__(256) k_final(
    const float* __restrict__ latent, const int* __restrict__ qseq,
    const float* __restrict__ la_W1, const float* __restrict__ la_b1,
    const float* __restrict__ la_W2, const float* __restrict__ la_b2,
    const int* __restrict__ q2c,
    const float* __restrict__ disc, const float* __restrict__ qds,
    const float* __restrict__ wdk, float* __restrict__ out)
{
    __shared__ unsigned short s_w2[200 * 132];   // 52.8 KB
    __shared__ float s_b2[200];

    const int tid = threadIdx.x;
    for (int i = tid; i < 200 * 132; i += 256)
        s_w2[i] = __half_as_ushort(__float2half(la_W2[i]));
    for (int i = tid; i < 200; i += 256) s_b2[i] = la_b2[i];
    __syncthreads();

    int o = blockIdx.x * blockDim.x + tid;
    if (o >= BB * (TT - 1)) return;
    int b = o / (TT - 1), t = o - b * (TT - 1);

    const float* lat = latent + (size_t)(b * TT + t) * 64;
    float l[64];
    #pragma unroll
    for (int k4 = 0; k4 < 16; k4++) {
        float4 v = ((const float4*)lat)[k4];
        l[k4 * 4] = v.x; l[k4 * 4 + 1] = v.y; l[k4 * 4 + 2] = v.z; l[k4 * 4 + 3] = v.w;
    }

    int q = qseq[b * TT + t + 1];
    int c0 = q2c[q * 4], c1 = q2c[q * 4 + 1], c2 = q2c[q * 4 + 2], c3 = q2c[q * 4 + 3];
    const unsigned short* w0p = s_w2 + c0 * 132;
    const unsigned short* w1p = s_w2 + c1 * 132;
    const unsigned short* w2p = s_w2 + c2 * 132;
    const unsigned short* w3p = s_w2 + c3 * 132;

    float u0 = 0.f, u1 = 0.f, u2 = 0.f, u3 = 0.f;
    for (int m = 0; m < 132; m++) {
        float a = la_b1[m];
        const float* w = la_W1 + m * 64;
        #pragma unroll
        for (int k = 0; k < 64; k++) a += w[k] * l[k];
        float hm = fmaxf(a, 0.f);
        u0 += __half2float(__ushort_as_half(w0p[m])) * hm;
        u1 += __half2float(__ushort_as_half(w1p[m])) * hm;
        u2 += __half2float(__ushort_as_half(w2p[m])) * hm;
        u3 += __half2float(__ushort_as_half(w3p[m])) * hm;
    }

    float w0 = wdk[q * 4], w1 = wdk[q * 4 + 1], w2 = wdk[q * 4 + 2], w3 = wdk[q * 4 + 3];
    float us = w0 * sigm(u0 + s_b2[c0]) + w1 * sigm(u1 + s_b2[c1])
             + w2 * sigm(u2 + s_b2[c2]) + w3 * sigm(u3 + s_b2[c3]);
    float qs = qds[q];
    float y = disc[q] * (us - qs) / (qs + 1e-6f);
    out[o] = sigm(y);
}

// ---------------------------------------------------------------------------
extern "C" void kernel_launch(void* const* d_in, const int* in_sizes, int n_in,
                              void* d_out, int out_size, void* d_ws, size_t ws_size,
                              hipStream_t stream)
{
    const float* E_q    = (const float*)d_in[0];
    const float* E_c    = (const float*)d_in[1];
    const float* E_it   = (const float*)d_in[2];
    const float* E_ut   = (const float*)d_in[3];
    const float* E_nh   = (const float*)d_in[4];
    const float* W_fuse = (const float*)d_in[5];
    const float* b_fuse = (const float*)d_in[6];
    const float* W_ih   = (const float*)d_in[7];
    const float* b_ih   = (const float*)d_in[8];
    const float* W_hh   = (const float*)d_in[9];
    const float* b_hh   = (const float*)d_in[10];
    const float* qd_W1  = (const float*)d_in[11];
    const float* qd_b1  = (const float*)d_in[12];
    const float* qd_W2  = (const float*)d_in[13];
    const float* qd_b2  = (const float*)d_in[14];
    const float* la_W1  = (const float*)d_in[15];
    const float* la_b1  = (const float*)d_in[16];
    const float* la_W2  = (const float*)d_in[17];
    const float* la_b2  = (const float*)d_in[18];
    const float* dc_W1  = (const float*)d_in[19];
    const float* dc_b1  = (const float*)d_in[20];
    const float* dc_W2  = (const float*)d_in[21];
    const float* dc_b2  = (const float*)d_in[22];

    int off = (in_sizes[23] == QN * 200) ? 1 : 0;
    const int* qseq  = (const int*)d_in[23 + off];
    const int* cseq  = (const int*)d_in[24 + off];
    const int* itseq = (const int*)d_in[25 + off];
    const int* utseq = (const int*)d_in[26 + off];
    const int* nhseq = (const int*)d_in[27 + off];
    const int* naseq = (const int*)d_in[28 + off];
    const int* q2c   = (const int*)d_in[29 + off];
    const int* q2cm  = (const int*)d_in[30 + off];

    float* ws = (float*)d_ws;
    size_t o = 0;
    float* T_c  = ws + o; o += (size_t)201 * 192;
    float* Tit  = ws + o; o += (size_t)101 * 192;
    float* Tut  = ws + o; o += (size_t)101 * 192;
    float* Tnh  = ws + o; o += (size_t)101 * 192;
    float* Tna  = ws + o; o += (size_t)101 * 192;
    float* b0   = ws + o; o += 192;
    float* vc   = ws + o; o += 192;
    float* Xq   = ws + o; o += (size_t)QN * 192;
    float* disc = ws + o; o += QN;
    float* qds  = ws + o; o += QN;
    float* wdk  = ws + o; o += (size_t)QN * 4;
    float* latent = ws + o; o += (size_t)BB * TT * 64;

    float* outp = (float*)d_out;

    k_tables<<<606, 192, 0, stream>>>(E_c, E_it, E_ut, E_nh, W_fuse, b_fuse, W_ih, b_ih,
                                      T_c, Tit, Tut, Tnh, Tna, b0, vc);
    k_perq<<<(QN + QPB - 1) / QPB, 192, 0, stream>>>(E_q, W_ih, qd_W1, qd_b1, qd_W2, qd_b2,
                                                     dc_W1, dc_b1, dc_W2, dc_b2, q2c, q2cm, T_c,
                                                     Xq, disc, qds, wdk);
    k_gru<<<BB, 64, 0, stream>>>(W_hh, b_hh, Xq, Tit, Tut, Tnh, Tna, b0, vc,
                                 qseq, cseq, itseq, utseq, nhseq, naseq, latent);
    k_final<<<(BB * (TT - 1) + 255) / 256, 256, 0, stream>>>(latent, qseq, la_W1, la_b1,
                                                             la_W2, la_b2, q2c, disc, qds, wdk, outp);
}

// Round 13
// 324.609 us; speedup vs baseline: 1.1638x; 1.0343x over previous
//
#include <hip/hip_runtime.h>
#include <hip/hip_fp16.h>

// Problem constants
constexpr int QN  = 10001;   // questions (Q+1)
constexpr int BB  = 512;     // batch
constexpr int TT  = 200;     // seq len
constexpr int QPB = 32;      // questions per block in k_perq

__device__ __forceinline__ float sigm(float x) { return 1.f / (1.f + __expf(-x)); }
__device__ __forceinline__ float tanh_fast(float x) { return 1.f - 2.f / (1.f + __expf(2.f * x)); }

// f32 pair -> packed f16x2 (RTNE via v_cvt_f16_f32 default rounding)
__device__ __forceinline__ unsigned packh_rtne(float lo, float hi) {
    return ((unsigned)__half_as_ushort(__float2half(hi)) << 16) |
            (unsigned)__half_as_ushort(__float2half(lo));
}

typedef _Float16 half2_t __attribute__((ext_vector_type(2)));
typedef float f4v __attribute__((ext_vector_type(4)));
__device__ __forceinline__ half2_t u2h(unsigned u) {
    union { unsigned u; half2_t h; } x; x.u = u; return x.h;
}

// packed-f16 dot2: acc += w.lo*h.lo + w.hi*h.hi
#if __has_builtin(__builtin_amdgcn_fdot2)
__device__ __forceinline__ float fdot2u(unsigned wu, unsigned hu, float acc) {
    return __builtin_amdgcn_fdot2(u2h(wu), u2h(hu), acc, false);
}
#else
__device__ __forceinline__ float fdot2u(unsigned wu, unsigned hu, float acc) {
    float wlo = __half2float(__ushort_as_half((unsigned short)(wu & 0xffffu)));
    float whi = __half2float(__ushort_as_half((unsigned short)(wu >> 16)));
    float hlo = __half2float(__ushort_as_half((unsigned short)(hu & 0xffffu)));
    float hhi = __half2float(__ushort_as_half((unsigned short)(hu >> 16)));
    return acc + wlo * hlo + whi * hhi;
}
#endif

// ---------------------------------------------------------------------------
// Kernel 1: tiny precomputed tables. T_it/T_ut/T_nh/T_na INTERLEAVED
// [idx][lane][3] (gate rows r,z,n contiguous per lane) so k_gru gathers one
// dwordx4 per table. T_c stays linear (consumed only by k_perq).
// ---------------------------------------------------------------------------
__global__ void k_tables(const float* __restrict__ E_c, const float* __restrict__ E_it,
                         const float* __restrict__ E_ut, const float* __restrict__ E_nh,
                         const float* __restrict__ W_fuse, const float* __restrict__ b_fuse,
                         const float* __restrict__ W_ih, const float* __restrict__ b_ih,
                         float* __restrict__ T_c, float* __restrict__ T_it,
                         float* __restrict__ T_ut, float* __restrict__ T_nh, float* __restrict__ T_na,
                         float* __restrict__ bias0, float* __restrict__ Vcorr)
{
    int blk = blockIdx.x, j = threadIdx.x; // 192 threads
    __shared__ float s_e[64];
    __shared__ float s_t[64];
    const int ilv = (j & 63) * 3 + (j >> 6);   // interleaved slot for gate-row j

    if (blk < 201) {
        if (j < 64) s_e[j] = E_c[blk * 64 + j];
        __syncthreads();
        float a = 0.f;
        #pragma unroll
        for (int k = 0; k < 64; k++) a += W_ih[j * 320 + 64 + k] * s_e[k];
        T_c[blk * 192 + j] = a;             // linear
    } else if (blk < 302) {
        int r = blk - 201;
        if (j < 64) s_e[j] = E_it[r * 64 + j];
        __syncthreads();
        float a = 0.f;
        #pragma unroll
        for (int k = 0; k < 64; k++) a += W_ih[j * 320 + 192 + k] * s_e[k];
        T_it[r * 192 + ilv] = a;            // interleaved
    } else if (blk < 605) {
        int which = (blk - 302) / 101;
        int r     = (blk - 302) % 101;
        const float* E = (which == 0) ? E_ut : E_nh;
        int fofs = which * 64;
        if (j < 64) s_e[j] = E[r * 64 + j];
        __syncthreads();
        if (j < 64) {
            float a = 0.f;
            #pragma unroll
            for (int d = 0; d < 64; d++) a += W_fuse[j * 192 + fofs + d] * s_e[d];
            s_t[j] = a;
        }
        __syncthreads();
        float a = 0.f;
        #pragma unroll
        for (int e = 0; e < 64; e++) a += W_ih[j * 320 + 256 + e] * s_t[e];
        float* outp = (which == 0) ? T_ut : ((which == 1) ? T_nh : T_na);
        outp[r * 192 + ilv] = a;            // interleaved
    } else {
        float a = b_ih[j];
        #pragma unroll
        for (int e = 0; e < 64; e++) a += W_ih[j * 320 + 256 + e] * b_fuse[e];
        bias0[j] = a;
        float v = 0.f;
        #pragma unroll
        for (int k = 0; k < 64; k++) v += W_ih[j * 320 + 128 + k];
        Vcorr[j] = v;
    }
}

// ---------------------------------------------------------------------------
// Kernel 2: per-question precompute (r9 form). Xq written INTERLEAVED.
// ---------------------------------------------------------------------------
__global__ void __launch_bounds__(192) k_perq(
    const float* __restrict__ E_q, const float* __restrict__ W_ih,
    const float* __restrict__ qd_W1, const float* __restrict__ qd_b1,
    const float* __restrict__ qd_W2, const float* __restrict__ qd_b2,
    const float* __restrict__ dc_W1, const float* __restrict__ dc_b1,
    const float* __restrict__ dc_W2, const float* __restrict__ dc_b2,
    const int* __restrict__ q2c, const int* __restrict__ q2cm,
    const float* __restrict__ T_c,
    float* __restrict__ Xq, float* __restrict__ disc,
    float* __restrict__ qds, float* __restrict__ wdk)
{
    __shared__ float s_wbuf[192 * 66];
    __shared__ float s_qe[QPB][64];
    __shared__ float s_wq[QPB][4];
    __shared__ int   s_cq[QPB][4];
    __shared__ float s_hidw[3][136];

    const int tid = threadIdx.x, w = tid >> 6, l = tid & 63;
    const int q0 = blockIdx.x * QPB;

    for (int i = tid; i < 132 * 64; i += 192)
        s_wbuf[(i >> 6) * 66 + (i & 63)] = qd_W1[i];
    for (int i = tid; i < 32 * 64; i += 192)
        s_wbuf[(132 + (i >> 6)) * 66 + (i & 63)] = dc_W1[i];
    for (int i = tid; i < QPB * 64; i += 192) {
        int qq = i >> 6, q = q0 + qq;
        s_qe[qq][i & 63] = E_q[(q < QN ? q : 0) * 64 + (i & 63)];
    }
    __syncthreads();

    for (int qq = w; qq < QPB; qq += 3) {
        int q = q0 + qq;
        bool valid = q < QN;
        int qc = valid ? q : 0;
        int cc[4], mm[4];
        #pragma unroll
        for (int k = 0; k < 4; k++) { cc[k] = q2c[qc * 4 + k]; mm[k] = q2cm[qc * 4 + k]; }

        float qe[64];
        #pragma unroll
        for (int k4 = 0; k4 < 16; k4++) {
            float4 v = *(const float4*)(&s_qe[qq][k4 * 4]);
            qe[4 * k4] = v.x; qe[4 * k4 + 1] = v.y; qe[4 * k4 + 2] = v.z; qe[4 * k4 + 3] = v.w;
        }

        auto rowdot = [&](int r) {
            const float* wr = s_wbuf + r * 66;
            float a = 0.f;
            #pragma unroll
            for (int jj = 0; jj < 32; jj++) {
                float2 ww = *(const float2*)(wr + 2 * jj);
                a += ww.x * qe[2 * jj] + ww.y * qe[2 * jj + 1];
            }
            return a;
        };

        s_hidw[w][l]      = fmaxf(rowdot(l)      + qd_b1[l],      0.f);
        s_hidw[w][64 + l] = fmaxf(rowdot(64 + l) + qd_b1[64 + l], 0.f);
        if (l < 4)
            s_hidw[w][128 + l] = fmaxf(rowdot(128 + l) + qd_b1[128 + l], 0.f);
        float dch = 0.f;
        if (l < 32) dch = fmaxf(rowdot(132 + l) + dc_b1[l], 0.f);

        int g = l >> 4, li = l & 15;
        int c = cc[g];
        float acc = 0.f;
        #pragma unroll
        for (int i = 0; i < 9; i++) {
            int m = li + 16 * i;
            if (m < 132) acc += qd_W2[c * 132 + m] * s_hidw[w][m];
        }
        acc += __shfl_xor(acc, 1); acc += __shfl_xor(acc, 2);
        acc += __shfl_xor(acc, 4); acc += __shfl_xor(acc, 8);
        float r0 = __shfl(acc, 0), r1 = __shfl(acc, 16);
        float r2 = __shfl(acc, 32), r3 = __shfl(acc, 48);

        float raw[4] = { sigm(r0 + qd_b2[cc[0]]), sigm(r1 + qd_b2[cc[1]]),
                         sigm(r2 + qd_b2[cc[2]]), sigm(r3 + qd_b2[cc[3]]) };
        float rel[4];
        #pragma unroll
        for (int k = 0; k < 4; k++) rel[k] = raw[k] * (float)mm[k];
        float sr = rel[0] + rel[1] + rel[2] + rel[3] + 1e-6f;

        float qsum = 0.f, wdv[4];
        #pragma unroll
        for (int k = 0; k < 4; k++) {
            float wd = 0.f;
            if (mm[k]) {
                bool dup = false;
                for (int jj = 0; jj < k; jj++)
                    if (mm[jj] && cc[jj] == cc[k]) dup = true;
                if (!dup) { wd = 1.f; qsum += raw[k]; }
            }
            wdv[k] = wd;
        }
        if (l < 4) { s_wq[qq][l] = rel[l] / sr; s_cq[qq][l] = cc[l]; }
        if (valid) {
            if (l < 4) wdk[q * 4 + l] = wdv[l];
            if (l == 0) qds[q] = qsum;
        }

        float dv = (l < 32) ? dch * dc_W2[l] : 0.f;
        dv += __shfl_xor(dv, 1);  dv += __shfl_xor(dv, 2);
        dv += __shfl_xor(dv, 4);  dv += __shfl_xor(dv, 8);
        dv += __shfl_xor(dv, 16);
        if (valid && l == 0) disc[q] = sigm(dv + dc_b2[0]) * 10.f;
    }

    __syncthreads();
    for (int i = tid; i < 192 * 64; i += 192) {
        int r = i >> 6, k = i & 63;
        s_wbuf[r * 66 + k] = W_ih[r * 320 + k];
    }
    __syncthreads();

    for (int qq = w; qq < QPB; qq += 3) {
        int q = q0 + qq;
        if (q >= QN) continue;

        float qe[64];
        #pragma unroll
        for (int k4 = 0; k4 < 16; k4++) {
            float4 v = *(const float4*)(&s_qe[qq][k4 * 4]);
            qe[4 * k4] = v.x; qe[4 * k4 + 1] = v.y; qe[4 * k4 + 2] = v.z; qe[4 * k4 + 3] = v.w;
        }
        float wq[4]; int cq[4];
        #pragma unroll
        for (int k = 0; k < 4; k++) { wq[k] = s_wq[qq][k]; cq[k] = s_cq[qq][k]; }

        #pragma unroll
        for (int rr = 0; rr < 3; rr++) {
            int row = rr * 64 + l;
            const float* wr = s_wbuf + row * 66;
            float a = 0.f;
            #pragma unroll
            for (int jj = 0; jj < 32; jj++) {
                float2 ww = *(const float2*)(wr + 2 * jj);
                a += ww.x * qe[2 * jj] + ww.y * qe[2 * jj + 1];
            }
            #pragma unroll
            for (int k = 0; k < 4; k++) a += wq[k] * T_c[cq[k] * 192 + row];
            Xq[q * 192 + l * 3 + rr] = a;   // interleaved
        }
    }
}

// ---------------------------------------------------------------------------
// Kernel 3 v13 (= v12 with macro fix): one wave per sample + hand-scheduled
// async gather pipeline. Interleaved tables -> 5 x global_load_dwordx4 per
// step via volatile inline asm (cannot be sunk), 4 static sets A-D refilled
// for t+4, counted s_waitcnt vmcnt(15) per step. Epilogue 15/10/5/0.
// ---------------------------------------------------------------------------
__global__ void
__launch_bounds__(64)
__attribute__((amdgpu_waves_per_eu(1, 1)))
k_gru(
    const float* __restrict__ W_hh, const float* __restrict__ b_hh,
    const float* __restrict__ XqI, const float* __restrict__ TitI, const float* __restrict__ TutI,
    const float* __restrict__ TnhI, const float* __restrict__ TnaI,
    const float* __restrict__ b0, const float* __restrict__ vc,
    const int* __restrict__ qseq, const int* __restrict__ cseq, const int* __restrict__ itseq,
    const int* __restrict__ utseq, const int* __restrict__ nhseq, const int* __restrict__ naseq,
    float* __restrict__ latent)
{
    const int j = threadIdx.x, b = blockIdx.x;
    const int j3 = 3 * j;

    __shared__ unsigned s_hp[32];     // h as packed f16 pairs (128 B)
    __shared__ int s_ix[6 * TT];      // q | c | it | ut | nh | na

    const int base = b * TT;
    for (int i = j; i < TT; i += 64) {
        s_ix[i]          = qseq[base + i];
        s_ix[TT + i]     = cseq[base + i];
        s_ix[2 * TT + i] = itseq[base + i];
        s_ix[3 * TT + i] = utseq[base + i];
        s_ix[4 * TT + i] = nhseq[base + i];
        s_ix[5 * TT + i] = naseq[base + i];
    }

    // lane j's three gate rows of W_hh, packed f16: 96 VGPRs
    unsigned wr[32], wz[32], wn[32];
    {
        const float4* p0 = (const float4*)(W_hh + j * 64);
        const float4* p1 = (const float4*)(W_hh + (64 + j) * 64);
        const float4* p2 = (const float4*)(W_hh + (128 + j) * 64);
        #pragma unroll
        for (int k = 0; k < 16; k++) {
            float4 a = p0[k], bq = p1[k], c = p2[k];
            wr[2 * k] = packh_rtne(a.x, a.y);  wr[2 * k + 1] = packh_rtne(a.z, a.w);
            wz[2 * k] = packh_rtne(bq.x, bq.y); wz[2 * k + 1] = packh_rtne(bq.z, bq.w);
            wn[2 * k] = packh_rtne(c.x, c.y);  wn[2 * k + 1] = packh_rtne(c.z, c.w);
        }
    }
    #pragma unroll
    for (int k = 0; k < 32; k++)
        asm volatile("" : "+v"(wr[k]), "+v"(wz[k]), "+v"(wn[k]));

    const float bhr = b_hh[j], bhz = b_hh[64 + j], bhn = b_hh[128 + j];
    const float b0r = b0[j],   b0z = b0[64 + j],   b0n = b0[128 + j];
    const float vcr = vc[j],   vcz = vc[64 + j],   vcn = vc[128 + j];

    if (j < 32) s_hp[j] = 0u;
    float hj = 0.f;

    // 4 static in-flight sets, 5 dwordx4 each (.xyz = r,z,n rows; .w junk)
    f4v A0, A1, A2, A3, A4;  float cA;
    f4v B0, B1, B2, B3, B4;  float cB;
    f4v C0, C1, C2, C3, C4;  float cC;
    f4v D0, D1, D2, D3, D4;  float cD;

#define GISSUE(P, CC, tt) { \
        int q_ = s_ix[tt], c_ = s_ix[TT + tt], it_ = s_ix[2 * TT + tt]; \
        int ut_ = s_ix[3 * TT + tt], nh_ = s_ix[4 * TT + tt], na_ = s_ix[5 * TT + tt]; \
        CC = (float)c_; \
        asm volatile("global_load_dwordx4 %0, %1, off" : "=v"(P##0) : "v"(XqI  + q_  * 192 + j3)); \
        asm volatile("global_load_dwordx4 %0, %1, off" : "=v"(P##1) : "v"(TitI + it_ * 192 + j3)); \
        asm volatile("global_load_dwordx4 %0, %1, off" : "=v"(P##2) : "v"(TutI + ut_ * 192 + j3)); \
        asm volatile("global_load_dwordx4 %0, %1, off" : "=v"(P##3) : "v"(TnhI + nh_ * 192 + j3)); \
        asm volatile("global_load_dwordx4 %0, %1, off" : "=v"(P##4) : "v"(TnaI + na_ * 192 + j3)); \
    }

#define STEP(P, CC, tcur, WN, REF) { \
        asm volatile("s_waitcnt vmcnt(" WN ")" ::: "memory"); \
        float xr = b0r + CC * vcr + ((((P##0).x + (P##1).x) + ((P##2).x + (P##3).x)) + (P##4).x); \
        float xz = b0z + CC * vcz + ((((P##0).y + (P##1).y) + ((P##2).y + (P##3).y)) + (P##4).y); \
        float xn = b0n + CC * vcn + ((((P##0).z + (P##1).z) + ((P##2).z + (P##3).z)) + (P##4).z); \
        asm volatile("" :: "v"((P##0).w), "v"((P##1).w), "v"((P##2).w), "v"((P##3).w), "v"((P##4).w)); \
        if (REF) GISSUE(P, CC, (tcur) + 4); \
        float ar0 = 0.f, ar1 = 0.f, ar2 = 0.f, ar3 = 0.f; \
        float az0 = 0.f, az1 = 0.f, az2 = 0.f, az3 = 0.f; \
        float an0 = 0.f, an1 = 0.f, an2 = 0.f, an3 = 0.f; \
        const uint4* hp4 = (const uint4*)s_hp; \
        _Pragma("unroll") \
        for (int k4 = 0; k4 < 8; k4++) { \
            uint4 hh = hp4[k4]; \
            ar0 = fdot2u(wr[4 * k4 + 0], hh.x, ar0); \
            ar1 = fdot2u(wr[4 * k4 + 1], hh.y, ar1); \
            ar2 = fdot2u(wr[4 * k4 + 2], hh.z, ar2); \
            ar3 = fdot2u(wr[4 * k4 + 3], hh.w, ar3); \
            az0 = fdot2u(wz[4 * k4 + 0], hh.x, az0); \
            az1 = fdot2u(wz[4 * k4 + 1], hh.y, az1); \
            az2 = fdot2u(wz[4 * k4 + 2], hh.z, az2); \
            az3 = fdot2u(wz[4 * k4 + 3], hh.w, az3); \
            an0 = fdot2u(wn[4 * k4 + 0], hh.x, an0); \
            an1 = fdot2u(wn[4 * k4 + 1], hh.y, an1); \
            an2 = fdot2u(wn[4 * k4 + 2], hh.z, an2); \
            an3 = fdot2u(wn[4 * k4 + 3], hh.w, an3); \
        } \
        float ar = ((ar0 + ar1) + (ar2 + ar3)) + bhr; \
        float az = ((az0 + az1) + (az2 + az3)) + bhz; \
        float an = ((an0 + an1) + (an2 + an3)) + bhn; \
        float r = sigm(xr + ar); \
        float z = sigm(xz + az); \
        float n = tanh_fast(xn + r * an); \
        hj = (1.f - z) * n + z * hj; \
        latent[(size_t)(base + (tcur)) * 64 + j] = hj; \
        float hnb = __shfl_xor(hj, 1); \
        unsigned pk = (j & 1) ? packh_rtne(hnb, hj) : packh_rtne(hj, hnb); \
        if (!(j & 1)) s_hp[j >> 1] = pk; \
    }

    GISSUE(A, cA, 0);
    GISSUE(B, cB, 1);
    GISSUE(C, cC, 2);
    GISSUE(D, cD, 3);

    for (int t = 0; t < TT - 4; t += 4) {
        STEP(A, cA, t,     "15", 1);
        STEP(B, cB, t + 1, "15", 1);
        STEP(C, cC, t + 2, "15", 1);
        STEP(D, cD, t + 3, "15", 1);
    }
    STEP(A, cA, TT - 4, "15", 0);
    STEP(B, cB, TT - 3, "10", 0);
    STEP(C, cC, TT - 2, "5",  0);
    STEP(D, cD, TT - 1, "0",  0);
#undef STEP
#undef GISSUE
}

// ---------------------------------------------------------------------------
// Kernel 4: readout with la_W2 staged in LDS as f16 (r11 form, unchanged).
// ---------------------------------------------------------------------------
__global__ void __launch_bounds__(256) k_final(
    const float* __restrict__ latent, const int* __restrict__ qseq,
    const float* __restrict__ la_W1, const float* __restrict__ la_b1,
    const float* __restrict__ la_W2, const float* __restrict__ la_b2,
    const int* __restrict__ q2c,
    const float* __restrict__ disc, const float* __restrict__ qds,
    const float* __restrict__ wdk, float* __restrict__ out)
{
    __shared__ unsigned short s_w2[200 * 132];   // 52.8 KB
    __shared__ float s_b2[200];

    const int tid = threadIdx.x;
    for (int i = tid; i < 200 * 132; i += 256)
        s_w2[i] = __half_as_ushort(__float2half(la_W2[i]));
    for (int i = tid; i < 200; i += 256) s_b2[i] = la_b2[i];
    __syncthreads();

    int o = blockIdx.x * blockDim.x + tid;
    if (o >= BB * (TT - 1)) return;
    int b = o / (TT - 1), t = o - b * (TT - 1);

    const float* lat = latent + (size_t)(b * TT + t) * 64;
    float l[64];
    #pragma unroll
    for (int k4 = 0; k4 < 16; k4++) {
        float4 v = ((const float4*)lat)[k4];
        l[k4 * 4] = v.x; l[k4 * 4 + 1] = v.y; l[k4 * 4 + 2] = v.z; l[k4 * 4 + 3] = v.w;
    }

    int q = qseq[b * TT + t + 1];
    int c0 = q2c[q * 4], c1 = q2c[q * 4 + 1], c2 = q2c[q * 4 + 2], c3 = q2c[q * 4 + 3];
    const unsigned short* w0p = s_w2 + c0 * 132;
    const unsigned short* w1p = s_w2 + c1 * 132;
    const unsigned short* w2p = s_w2 + c2 * 132;
    const unsigned short* w3p = s_w2 + c3 * 132;

    float u0 = 0.f, u1 = 0.f, u2 = 0.f, u3 = 0.f;
    for (int m = 0; m < 132; m++) {
        float a = la_b1[m];
        const float* w = la_W1 + m * 64;
        #pragma unroll
        for (int k = 0; k < 64; k++) a += w[k] * l[k];
        float hm = fmaxf(a, 0.f);
        u0 += __half2float(__ushort_as_half(w0p[m])) * hm;
        u1 += __half2float(__ushort_as_half(w1p[m])) * hm;
        u2 += __half2float(__ushort_as_half(w2p[m])) * hm;
        u3 += __half2float(__ushort_as_half(w3p[m])) * hm;
    }

    float w0 = wdk[q * 4], w1 = wdk[q * 4 + 1], w2 = wdk[q * 4 + 2], w3 = wdk[q * 4 + 3];
    float us = w0 * sigm(u0 + s_b2[c0]) + w1 * sigm(u1 + s_b2[c1])
             + w2 * sigm(u2 + s_b2[c2]) + w3 * sigm(u3 + s_b2[c3]);
    float qs = qds[q];
    float y = disc[q] * (us - qs) / (qs + 1e-6f);
    out[o] = sigm(y);
}

// ---------------------------------------------------------------------------
extern "C" void kernel_launch(void* const* d_in, const int* in_sizes, int n_in,
                              void* d_out, int out_size, void* d_ws, size_t ws_size,
                              hipStream_t stream)
{
    const float* E_q    = (const float*)d_in[0];
    const float* E_c    = (const float*)d_in[1];
    const float* E_it   = (const float*)d_in[2];
    const float* E_ut   = (const float*)d_in[3];
    const float* E_nh   = (const float*)d_in[4];
    const float* W_fuse = (const float*)d_in[5];
    const float* b_fuse = (const float*)d_in[6];
    const float* W_ih   = (const float*)d_in[7];
    const float* b_ih   = (const float*)d_in[8];
    const float* W_hh   = (const float*)d_in[9];
    const float* b_hh   = (const float*)d_in[10];
    const float* qd_W1  = (const float*)d_in[11];
    const float* qd_b1  = (const float*)d_in[12];
    const float* qd_W2  = (const float*)d_in[13];
    const float* qd_b2  = (const float*)d_in[14];
    const float* la_W1  = (const float*)d_in[15];
    const float* la_b1  = (const float*)d_in[16];
    const float* la_W2  = (const float*)d_in[17];
    const float* la_b2  = (const float*)d_in[18];
    const float* dc_W1  = (const float*)d_in[19];
    const float* dc_b1  = (const float*)d_in[20];
    const float* dc_W2  = (const float*)d_in[21];
    const float* dc_b2  = (const float*)d_in[22];

    int off = (in_sizes[23] == QN * 200) ? 1 : 0;
    const int* qseq  = (const int*)d_in[23 + off];
    const int* cseq  = (const int*)d_in[24 + off];
    const int* itseq = (const int*)d_in[25 + off];
    const int* utseq = (const int*)d_in[26 + off];
    const int* nhseq = (const int*)d_in[27 + off];
    const int* naseq = (const int*)d_in[28 + off];
    const int* q2c   = (const int*)d_in[29 + off];
    const int* q2cm  = (const int*)d_in[30 + off];

    float* ws = (float*)d_ws;
    size_t o = 0;
    float* T_c  = ws + o; o += (size_t)201 * 192 + 4;
    float* Tit  = ws + o; o += (size_t)101 * 192 + 4;   // interleaved (+pad for dwordx4 overread)
    float* Tut  = ws + o; o += (size_t)101 * 192 + 4;
    float* Tnh  = ws + o; o += (size_t)101 * 192 + 4;
    float* Tna  = ws + o; o += (size_t)101 * 192 + 4;
    float* b0   = ws + o; o += 192;
    float* vc   = ws + o; o += 192;
    float* Xq   = ws + o; o += (size_t)QN * 192 + 4;    // interleaved (+pad)
    float* disc = ws + o; o += QN;
    float* qds  = ws + o; o += QN;
    float* wdk  = ws + o; o += (size_t)QN * 4;
    float* latent = ws + o; o += (size_t)BB * TT * 64;

    float* outp = (float*)d_out;

    k_tables<<<606, 192, 0, stream>>>(E_c, E_it, E_ut, E_nh, W_fuse, b_fuse, W_ih, b_ih,
                                      T_c, Tit, Tut, Tnh, Tna, b0, vc);
    k_perq<<<(QN + QPB - 1) / QPB, 192, 0, stream>>>(E_q, W_ih, qd_W1, qd_b1, qd_W2, qd_b2,
                                                     dc_W1, dc_b1, dc_W2, dc_b2, q2c, q2cm, T_c,
                                                     Xq, disc, qds, wdk);
    k_gru<<<BB, 64, 0, stream>>>(W_hh, b_hh, Xq, Tit, Tut, Tnh, Tna, b0, vc,
                                 qseq, cseq, itseq, utseq, nhseq, naseq, latent);
    k_final<<<(BB * (TT - 1) + 255) / 256, 256, 0, stream>>>(latent, qseq, la_W1, la_b1,
                                                             la_W2, la_b2, q2c, disc, qds, wdk, outp);
}